// Round 1
// baseline (2129.100 us; speedup 1.0000x reference)
//
#include <hip/hip_runtime.h>
#include <math.h>

// Problem constants
#define NB   8
#define CCH  256
#define PPX  2304            // 48*48
#define CPb  (CCH*PPX)       // per-batch C*P = 589824
#define NTOT (NB*CPb)        // 4718592
#define PSQ  (PPX*PPX)       // 5308416

// GEMM tile config
#define BM 64
#define BN 64
#define BK 16
#define PAD 4                // pad to 68 floats/row: 16B-aligned rows, no 4-way conflicts

__device__ __forceinline__ float relu_(float x){ return x > 0.f ? x : 0.f; }

// ---------------------------------------------------------------------------
// QKV: out[b,m,n] = sum_k W[m,k] * x[b,k,n] + bias[m]   (NN GEMM, K=256)
// ---------------------------------------------------------------------------
__global__ __launch_bounds__(256) void gemm_qkv(
    const float* __restrict__ Wm, const float* __restrict__ bias,
    const float* __restrict__ x, float* __restrict__ out)
{
  const int b  = blockIdx.z;
  const float* Bp = x + (long)b * CPb;
  float* Op = out + (long)b * CPb;
  const int m0 = blockIdx.y * BM, n0 = blockIdx.x * BN;
  const int tx = threadIdx.x, ty = threadIdx.y;
  const int t  = ty * 16 + tx;

  __shared__ float As[BK][BM + PAD];
  __shared__ float Bs[BK][BN + PAD];
  float acc[4][4] = {};

  const int K = CCH;
  for (int k0 = 0; k0 < K; k0 += BK) {
    // A tile: rows m0..m0+63, cols k0..k0+15 -> store transposed As[k][m]
    const int ar = t >> 2, ac = (t & 3) * 4;
    float4 av = *(const float4*)&Wm[(long)(m0 + ar) * K + k0 + ac];
    As[ac + 0][ar] = av.x; As[ac + 1][ar] = av.y;
    As[ac + 2][ar] = av.z; As[ac + 3][ar] = av.w;
    // B tile: rows k0..k0+15, cols n0..n0+63 -> direct Bs[k][n]
    const int br = t >> 4, bc = (t & 15) * 4;
    float4 bv = *(const float4*)&Bp[(long)(k0 + br) * PPX + n0 + bc];
    *(float4*)&Bs[br][bc] = bv;
    __syncthreads();
    #pragma unroll
    for (int kk = 0; kk < BK; kk++) {
      const float4 a4 = *(const float4*)&As[kk][ty * 4];
      const float4 b4 = *(const float4*)&Bs[kk][tx * 4];
      const float ae[4] = {a4.x, a4.y, a4.z, a4.w};
      const float be[4] = {b4.x, b4.y, b4.z, b4.w};
      #pragma unroll
      for (int i = 0; i < 4; i++)
        #pragma unroll
        for (int j = 0; j < 4; j++)
          acc[i][j] += ae[i] * be[j];
    }
    __syncthreads();
  }
  #pragma unroll
  for (int i = 0; i < 4; i++) {
    const int m = m0 + ty * 4 + i;
    const float bi = bias[m];
    #pragma unroll
    for (int j = 0; j < 4; j++)
      Op[(long)m * PPX + n0 + tx * 4 + j] = acc[i][j] + bi;
  }
}

// ---------------------------------------------------------------------------
// Scores (transposed): St[j,i] = sum_c k[b,c,j] * q[b,c,i]    (TN GEMM, K=256)
// ---------------------------------------------------------------------------
__global__ __launch_bounds__(256) void gemm_scores(
    const float* __restrict__ kbuf, const float* __restrict__ qbuf,
    float* __restrict__ st, long sstride, int bstart)
{
  const int b = bstart + blockIdx.z;
  const float* Ap = kbuf + (long)b * CPb;  // A[k=c][m=j]
  const float* Bp = qbuf + (long)b * CPb;  // B[k=c][n=i]
  float* Sp = st + (long)blockIdx.z * sstride;
  const int m0 = blockIdx.y * BM, n0 = blockIdx.x * BN;
  const int tx = threadIdx.x, ty = threadIdx.y;
  const int t  = ty * 16 + tx;

  __shared__ float As[BK][BM + PAD];
  __shared__ float Bs[BK][BN + PAD];
  float acc[4][4] = {};

  for (int k0 = 0; k0 < CCH; k0 += BK) {
    const int r = t >> 4, cidx = (t & 15) * 4;
    float4 av = *(const float4*)&Ap[(long)(k0 + r) * PPX + m0 + cidx];
    *(float4*)&As[r][cidx] = av;
    float4 bv = *(const float4*)&Bp[(long)(k0 + r) * PPX + n0 + cidx];
    *(float4*)&Bs[r][cidx] = bv;
    __syncthreads();
    #pragma unroll
    for (int kk = 0; kk < BK; kk++) {
      const float4 a4 = *(const float4*)&As[kk][ty * 4];
      const float4 b4 = *(const float4*)&Bs[kk][tx * 4];
      const float ae[4] = {a4.x, a4.y, a4.z, a4.w};
      const float be[4] = {b4.x, b4.y, b4.z, b4.w};
      #pragma unroll
      for (int i = 0; i < 4; i++)
        #pragma unroll
        for (int j = 0; j < 4; j++)
          acc[i][j] += ae[i] * be[j];
    }
    __syncthreads();
  }
  #pragma unroll
  for (int i = 0; i < 4; i++)
    #pragma unroll
    for (int j = 0; j < 4; j++)
      Sp[(long)(m0 + ty * 4 + i) * PPX + n0 + tx * 4 + j] = acc[i][j];
}

// ---------------------------------------------------------------------------
// Row softmax over St rows (axis i, contiguous). One block per row.
// ---------------------------------------------------------------------------
__global__ __launch_bounds__(256) void softmax_rows(float* __restrict__ st, long sstride)
{
  float* row = st + (long)blockIdx.y * sstride + (long)blockIdx.x * PPX;
  const int t = threadIdx.x;
  float v[9];
  float m = -1e30f;
  #pragma unroll
  for (int u = 0; u < 9; u++) { v[u] = row[t + 256 * u]; m = fmaxf(m, v[u]); }

  __shared__ float red[256];
  red[t] = m; __syncthreads();
  for (int s = 128; s > 0; s >>= 1) {
    if (t < s) red[t] = fmaxf(red[t], red[t + s]);
    __syncthreads();
  }
  m = red[0]; __syncthreads();

  float sum = 0.f;
  #pragma unroll
  for (int u = 0; u < 9; u++) { v[u] = expf(v[u] - m); sum += v[u]; }
  red[t] = sum; __syncthreads();
  for (int s = 128; s > 0; s >>= 1) {
    if (t < s) red[t] += red[t + s];
    __syncthreads();
  }
  const float inv = 1.f / red[0];
  #pragma unroll
  for (int u = 0; u < 9; u++) row[t + 256 * u] = v[u] * inv;
}

// ---------------------------------------------------------------------------
// PV: attn[b,c,j] = delta * sum_i v[b,c,i]*Wt[j,i] + ftr[b,c,j]  (NT, K=2304)
// ---------------------------------------------------------------------------
__global__ __launch_bounds__(256) void gemm_pv(
    const float* __restrict__ vbuf, const float* __restrict__ wt, long sstride,
    const float* __restrict__ ftr, const float* __restrict__ delta,
    float* __restrict__ attn, int bstart)
{
  const int b = bstart + blockIdx.z;
  const float* Ap = vbuf + (long)b * CPb;              // A[m=c][k=i]
  const float* Bp = wt + (long)blockIdx.z * sstride;   // B[n=j][k=i]
  float* Op = attn + (long)b * CPb;
  const float* Fp = ftr + (long)b * CPb;
  const int m0 = blockIdx.y * BM, n0 = blockIdx.x * BN;
  const int tx = threadIdx.x, ty = threadIdx.y;
  const int t  = ty * 16 + tx;

  __shared__ float As[BK][BM + PAD];
  __shared__ float Bs[BK][BN + PAD];
  float acc[4][4] = {};

  for (int k0 = 0; k0 < PPX; k0 += BK) {
    const int ar = t >> 2, ac = (t & 3) * 4;
    float4 av = *(const float4*)&Ap[(long)(m0 + ar) * PPX + k0 + ac];
    As[ac + 0][ar] = av.x; As[ac + 1][ar] = av.y;
    As[ac + 2][ar] = av.z; As[ac + 3][ar] = av.w;
    float4 bv = *(const float4*)&Bp[(long)(n0 + ar) * PPX + k0 + ac];
    Bs[ac + 0][ar] = bv.x; Bs[ac + 1][ar] = bv.y;
    Bs[ac + 2][ar] = bv.z; Bs[ac + 3][ar] = bv.w;
    __syncthreads();
    #pragma unroll
    for (int kk = 0; kk < BK; kk++) {
      const float4 a4 = *(const float4*)&As[kk][ty * 4];
      const float4 b4 = *(const float4*)&Bs[kk][tx * 4];
      const float ae[4] = {a4.x, a4.y, a4.z, a4.w};
      const float be[4] = {b4.x, b4.y, b4.z, b4.w};
      #pragma unroll
      for (int i = 0; i < 4; i++)
        #pragma unroll
        for (int j = 0; j < 4; j++)
          acc[i][j] += ae[i] * be[j];
    }
    __syncthreads();
  }
  const float d0 = delta[0];
  #pragma unroll
  for (int i = 0; i < 4; i++)
    #pragma unroll
    for (int j = 0; j < 4; j++) {
      const long idx = (long)(m0 + ty * 4 + i) * PPX + n0 + tx * 4 + j;
      Op[idx] = d0 * acc[i][j] + Fp[idx];
    }
}

// ---------------------------------------------------------------------------
// conv3x3 (SAME) + BN(eval) + ReLU as implicit GEMM. M=256, N=B*H*W, K=Cin*9
// ---------------------------------------------------------------------------
__global__ __launch_bounds__(256) void conv3_bn_relu(
    const float* __restrict__ in, int Cin,
    const float* __restrict__ w,
    const float* __restrict__ gamma, const float* __restrict__ beta,
    const float* __restrict__ mean,  const float* __restrict__ var,
    float* __restrict__ out)
{
  const int K = Cin * 9;
  const int m0 = blockIdx.y * BM, n0 = blockIdx.x * BN;
  const int bidx = n0 / PPX;          // 64-wide n-tile never crosses a batch
  const int pbase = bidx * PPX;
  const int tx = threadIdx.x, ty = threadIdx.y;
  const int t  = ty * 16 + tx;

  __shared__ float As[BK][BM + PAD];
  __shared__ float Bs[BK][BN + PAD];
  float acc[4][4] = {};

  for (int k0 = 0; k0 < K; k0 += BK) {
    // A: weights [256][K] row-major, transposed store
    const int ar = t >> 2, ac = (t & 3) * 4;
    float4 av = *(const float4*)&w[(long)(m0 + ar) * K + k0 + ac];
    As[ac + 0][ar] = av.x; As[ac + 1][ar] = av.y;
    As[ac + 2][ar] = av.z; As[ac + 3][ar] = av.w;
    // B: im2col gather
    const int kk = t >> 4, nl = (t & 15) * 4;
    const int k = k0 + kk;
    const int c = k / 9;
    const int r = k - c * 9;
    const int dy = r / 3 - 1;
    const int dx = r - (r / 3) * 3 - 1;
    const float* chan = in + ((long)bidx * Cin + c) * PPX;
    #pragma unroll
    for (int j = 0; j < 4; j++) {
      const int n = n0 + nl + j;
      const int p = n - pbase;
      const int y = p / 48;
      const int x = p - y * 48;
      const int yy = y + dy, xx = x + dx;
      float val = (yy >= 0 && yy < 48 && xx >= 0 && xx < 48)
                      ? chan[yy * 48 + xx] : 0.f;
      Bs[kk][nl + j] = val;
    }
    __syncthreads();
    #pragma unroll
    for (int kk2 = 0; kk2 < BK; kk2++) {
      const float4 a4 = *(const float4*)&As[kk2][ty * 4];
      const float4 b4 = *(const float4*)&Bs[kk2][tx * 4];
      const float ae[4] = {a4.x, a4.y, a4.z, a4.w};
      const float be[4] = {b4.x, b4.y, b4.z, b4.w};
      #pragma unroll
      for (int i = 0; i < 4; i++)
        #pragma unroll
        for (int j = 0; j < 4; j++)
          acc[i][j] += ae[i] * be[j];
    }
    __syncthreads();
  }
  #pragma unroll
  for (int i = 0; i < 4; i++) {
    const int mo = m0 + ty * 4 + i;
    const float inv = gamma[mo] * rsqrtf(var[mo] + 1e-5f);
    const float ad  = beta[mo] - mean[mo] * inv;
    #pragma unroll
    for (int j = 0; j < 4; j++) {
      const int n = n0 + tx * 4 + j;
      const int p = n - pbase;
      out[((long)bidx * CCH + mo) * PPX + p] = relu_(acc[i][j] * inv + ad);
    }
  }
}

// ---------------------------------------------------------------------------
// avg/max pool3 (SAME, count_include_pad) * sigmoid(act1) -> cat [B,512,H,W]
// ---------------------------------------------------------------------------
__global__ __launch_bounds__(256) void pool_gate_cat(
    const float* __restrict__ ftr, const float* __restrict__ act1,
    float* __restrict__ cat)
{
  const int idx = blockIdx.x * 256 + threadIdx.x;   // < NTOT
  const int p  = idx % PPX;
  const int bc = idx / PPX;                          // b*256 + c
  const int y = p / 48, x = p - (p / 48) * 48;
  const float* base = ftr + (long)bc * PPX;
  float s = 0.f, mx = -1e30f;
  #pragma unroll
  for (int dy = -1; dy <= 1; dy++) {
    const int yy = y + dy;
    if (yy < 0 || yy >= 48) continue;
    #pragma unroll
    for (int dx = -1; dx <= 1; dx++) {
      const int xx = x + dx;
      if (xx < 0 || xx >= 48) continue;
      const float f = base[yy * 48 + xx];
      s += f; mx = fmaxf(mx, f);
    }
  }
  const float g = act1[idx];
  const float gate = 1.f / (1.f + expf(-g));
  const int b = bc >> 8, c = bc & 255;
  const long o1 = ((long)b * 512 + c) * PPX + p;
  cat[o1] = mx * gate;                   // ftr_max first
  cat[o1 + (long)256 * PPX] = s * (1.f / 9.f) * gate;  // then ftr_avg
}

// ---------------------------------------------------------------------------
extern "C" void kernel_launch(void* const* d_in, const int* in_sizes, int n_in,
                              void* d_out, int out_size, void* d_ws, size_t ws_size,
                              hipStream_t stream)
{
  const float* ftr  = (const float*)d_in[0];
  const float* wq   = (const float*)d_in[1];
  const float* bq   = (const float*)d_in[2];
  const float* wk   = (const float*)d_in[3];
  const float* bk   = (const float*)d_in[4];
  const float* wv   = (const float*)d_in[5];
  const float* bv   = (const float*)d_in[6];
  const float* delta= (const float*)d_in[7];
  const float* w1   = (const float*)d_in[8];
  const float* g1   = (const float*)d_in[9];
  const float* b1   = (const float*)d_in[10];
  const float* m1   = (const float*)d_in[11];
  const float* v1   = (const float*)d_in[12];
  const float* w2   = (const float*)d_in[13];
  const float* g2   = (const float*)d_in[14];
  const float* b2   = (const float*)d_in[15];
  const float* m2   = (const float*)d_in[16];
  const float* v2   = (const float*)d_in[17];
  float* out = (float*)d_out;
  float* ws  = (float*)d_ws;

  float* q  = ws;
  float* kb = ws + (long)NTOT;
  float* vb = ws + 2L * NTOT;
  float* sc = ws + 3L * NTOT;

  const size_t needA = ((size_t)3 * NTOT + (size_t)NB * PSQ) * 4;  // ~226.5 MB
  const bool modeA = ws_size >= needA;

  float *attn, *act1, *cat;
  if (modeA) {
    attn = q;        // q dead after scores
    act1 = kb;       // k dead after scores
    cat  = sc;       // scores dead after PV
  } else {
    attn = sc + (long)PSQ;
    act1 = attn + (long)NTOT;
    cat  = act1 + (long)NTOT;
  }

  dim3 blk(16, 16);

  // QKV
  gemm_qkv<<<dim3(36, 4, 8), blk, 0, stream>>>(wq, bq, ftr, q);
  gemm_qkv<<<dim3(36, 4, 8), blk, 0, stream>>>(wk, bk, ftr, kb);
  gemm_qkv<<<dim3(36, 4, 8), blk, 0, stream>>>(wv, bv, ftr, vb);

  if (modeA) {
    gemm_scores<<<dim3(36, 36, 8), blk, 0, stream>>>(kb, q, sc, (long)PSQ, 0);
    softmax_rows<<<dim3(PPX, 8), 256, 0, stream>>>(sc, (long)PSQ);
    gemm_pv<<<dim3(36, 4, 8), blk, 0, stream>>>(vb, sc, (long)PSQ, ftr, delta, attn, 0);
  } else {
    for (int b = 0; b < NB; b++) {
      gemm_scores<<<dim3(36, 36, 1), blk, 0, stream>>>(kb, q, sc, 0L, b);
      softmax_rows<<<dim3(PPX, 1), 256, 0, stream>>>(sc, 0L);
      gemm_pv<<<dim3(36, 4, 1), blk, 0, stream>>>(vb, sc, 0L, ftr, delta, attn, b);
    }
  }

  // conv1 + BN + ReLU
  conv3_bn_relu<<<dim3(288, 4), blk, 0, stream>>>(attn, CCH, w1, g1, b1, m1, v1, act1);
  // pool + gate + concat
  pool_gate_cat<<<dim3(NTOT / 256), 256, 0, stream>>>(ftr, act1, cat);
  // conv2 + BN + ReLU -> out
  conv3_bn_relu<<<dim3(288, 4), blk, 0, stream>>>(cat, 2 * CCH, w2, g2, b2, m2, v2, out);
}

// Round 2
// 1102.779 us; speedup vs baseline: 1.9307x; 1.9307x over previous
//
#include <hip/hip_runtime.h>
#include <math.h>

// Problem constants
#define NB   8
#define CCH  256
#define PPX  2304            // 48*48
#define CPb  (CCH*PPX)       // per-batch C*P = 589824
#define NTOT (NB*CPb)        // 4718592
#define PSQ  (PPX*PPX)       // 5308416
#define PADIMG 2500          // 50*50 padded image

// fp32 GEMM tile config (attention path, unchanged this round)
#define BM 64
#define BN 64
#define BK 16
#define PAD 4

typedef short short8_t __attribute__((ext_vector_type(8)));
typedef float f4_t __attribute__((ext_vector_type(4)));

__device__ __forceinline__ float relu_(float x){ return x > 0.f ? x : 0.f; }

__device__ __forceinline__ unsigned short f2bf(float f) {
  unsigned int u = __builtin_bit_cast(unsigned int, f);
  u += 0x7fffu + ((u >> 16) & 1u);
  return (unsigned short)(u >> 16);
}
__device__ __forceinline__ float bf2f(unsigned short h) {
  unsigned int u = ((unsigned int)h) << 16;
  return __builtin_bit_cast(float, u);
}

// ---------------------------------------------------------------------------
// Weight repack: wr[tap][o][c] = bf16(w[o][c][tap]),  tap = ky*3+kx
// ---------------------------------------------------------------------------
__global__ __launch_bounds__(256) void repack_w(
    const float* __restrict__ w, unsigned short* __restrict__ wr, int Cin)
{
  const int idx = blockIdx.x * 256 + threadIdx.x;
  const int total = 9 * 256 * Cin;
  if (idx >= total) return;
  const int c = idx % Cin;
  const int rest = idx / Cin;
  const int o = rest % 256;
  const int tap = rest / 256;
  wr[idx] = f2bf(w[((size_t)o * Cin + c) * 9 + tap]);
}

// ---------------------------------------------------------------------------
// QKV: out[b,m,n] = sum_k W[m,k] * x[b,k,n] + bias[m]   (fp32, unchanged)
// ---------------------------------------------------------------------------
__global__ __launch_bounds__(256) void gemm_qkv(
    const float* __restrict__ Wm, const float* __restrict__ bias,
    const float* __restrict__ x, float* __restrict__ out)
{
  const int b  = blockIdx.z;
  const float* Bp = x + (long)b * CPb;
  float* Op = out + (long)b * CPb;
  const int m0 = blockIdx.y * BM, n0 = blockIdx.x * BN;
  const int tx = threadIdx.x, ty = threadIdx.y;
  const int t  = ty * 16 + tx;

  __shared__ float As[BK][BM + PAD];
  __shared__ float Bs[BK][BN + PAD];
  float acc[4][4] = {};

  const int K = CCH;
  for (int k0 = 0; k0 < K; k0 += BK) {
    const int ar = t >> 2, ac = (t & 3) * 4;
    float4 av = *(const float4*)&Wm[(long)(m0 + ar) * K + k0 + ac];
    As[ac + 0][ar] = av.x; As[ac + 1][ar] = av.y;
    As[ac + 2][ar] = av.z; As[ac + 3][ar] = av.w;
    const int br = t >> 4, bc = (t & 15) * 4;
    float4 bv = *(const float4*)&Bp[(long)(k0 + br) * PPX + n0 + bc];
    *(float4*)&Bs[br][bc] = bv;
    __syncthreads();
    #pragma unroll
    for (int kk = 0; kk < BK; kk++) {
      const float4 a4 = *(const float4*)&As[kk][ty * 4];
      const float4 b4 = *(const float4*)&Bs[kk][tx * 4];
      const float ae[4] = {a4.x, a4.y, a4.z, a4.w};
      const float be[4] = {b4.x, b4.y, b4.z, b4.w};
      #pragma unroll
      for (int i = 0; i < 4; i++)
        #pragma unroll
        for (int j = 0; j < 4; j++)
          acc[i][j] += ae[i] * be[j];
    }
    __syncthreads();
  }
  #pragma unroll
  for (int i = 0; i < 4; i++) {
    const int m = m0 + ty * 4 + i;
    const float bi = bias[m];
    #pragma unroll
    for (int j = 0; j < 4; j++)
      Op[(long)m * PPX + n0 + tx * 4 + j] = acc[i][j] + bi;
  }
}

// ---------------------------------------------------------------------------
// Scores (transposed): St[j,i] = sum_c k[b,c,j] * q[b,c,i]    (fp32)
// ---------------------------------------------------------------------------
__global__ __launch_bounds__(256) void gemm_scores(
    const float* __restrict__ kbuf, const float* __restrict__ qbuf,
    float* __restrict__ st, long sstride, int bstart)
{
  const int b = bstart + blockIdx.z;
  const float* Ap = kbuf + (long)b * CPb;
  const float* Bp = qbuf + (long)b * CPb;
  float* Sp = st + (long)blockIdx.z * sstride;
  const int m0 = blockIdx.y * BM, n0 = blockIdx.x * BN;
  const int tx = threadIdx.x, ty = threadIdx.y;
  const int t  = ty * 16 + tx;

  __shared__ float As[BK][BM + PAD];
  __shared__ float Bs[BK][BN + PAD];
  float acc[4][4] = {};

  for (int k0 = 0; k0 < CCH; k0 += BK) {
    const int r = t >> 4, cidx = (t & 15) * 4;
    float4 av = *(const float4*)&Ap[(long)(k0 + r) * PPX + m0 + cidx];
    *(float4*)&As[r][cidx] = av;
    float4 bv = *(const float4*)&Bp[(long)(k0 + r) * PPX + n0 + cidx];
    *(float4*)&Bs[r][cidx] = bv;
    __syncthreads();
    #pragma unroll
    for (int kk = 0; kk < BK; kk++) {
      const float4 a4 = *(const float4*)&As[kk][ty * 4];
      const float4 b4 = *(const float4*)&Bs[kk][tx * 4];
      const float ae[4] = {a4.x, a4.y, a4.z, a4.w};
      const float be[4] = {b4.x, b4.y, b4.z, b4.w};
      #pragma unroll
      for (int i = 0; i < 4; i++)
        #pragma unroll
        for (int j = 0; j < 4; j++)
          acc[i][j] += ae[i] * be[j];
    }
    __syncthreads();
  }
  #pragma unroll
  for (int i = 0; i < 4; i++)
    #pragma unroll
    for (int j = 0; j < 4; j++)
      Sp[(long)(m0 + ty * 4 + i) * PPX + n0 + tx * 4 + j] = acc[i][j];
}

// ---------------------------------------------------------------------------
// Row softmax over St rows (fp32, unchanged)
// ---------------------------------------------------------------------------
__global__ __launch_bounds__(256) void softmax_rows(float* __restrict__ st, long sstride)
{
  float* row = st + (long)blockIdx.y * sstride + (long)blockIdx.x * PPX;
  const int t = threadIdx.x;
  float v[9];
  float m = -1e30f;
  #pragma unroll
  for (int u = 0; u < 9; u++) { v[u] = row[t + 256 * u]; m = fmaxf(m, v[u]); }

  __shared__ float red[256];
  red[t] = m; __syncthreads();
  for (int s = 128; s > 0; s >>= 1) {
    if (t < s) red[t] = fmaxf(red[t], red[t + s]);
    __syncthreads();
  }
  m = red[0]; __syncthreads();

  float sum = 0.f;
  #pragma unroll
  for (int u = 0; u < 9; u++) { v[u] = expf(v[u] - m); sum += v[u]; }
  red[t] = sum; __syncthreads();
  for (int s = 128; s > 0; s >>= 1) {
    if (t < s) red[t] += red[t + s];
    __syncthreads();
  }
  const float inv = 1.f / red[0];
  #pragma unroll
  for (int u = 0; u < 9; u++) row[t + 256 * u] = v[u] * inv;
}

// ---------------------------------------------------------------------------
// PV: attn[b,c,j] = delta * sum_i v[b,c,i]*Wt[j,i] + ftr[b,c,j]
// -> writes PADDED bf16 image attn_p [B][256][50*50]
// ---------------------------------------------------------------------------
__global__ __launch_bounds__(256) void gemm_pv(
    const float* __restrict__ vbuf, const float* __restrict__ wt, long sstride,
    const float* __restrict__ ftr, const float* __restrict__ delta,
    unsigned short* __restrict__ attn_p, int bstart)
{
  const int b = bstart + blockIdx.z;
  const float* Ap = vbuf + (long)b * CPb;
  const float* Bp = wt + (long)blockIdx.z * sstride;
  const float* Fp = ftr + (long)b * CPb;
  const int m0 = blockIdx.y * BM, n0 = blockIdx.x * BN;
  const int tx = threadIdx.x, ty = threadIdx.y;
  const int t  = ty * 16 + tx;

  __shared__ float As[BK][BM + PAD];
  __shared__ float Bs[BK][BN + PAD];
  float acc[4][4] = {};

  for (int k0 = 0; k0 < PPX; k0 += BK) {
    const int ar = t >> 2, ac = (t & 3) * 4;
    float4 av = *(const float4*)&Ap[(long)(m0 + ar) * PPX + k0 + ac];
    As[ac + 0][ar] = av.x; As[ac + 1][ar] = av.y;
    As[ac + 2][ar] = av.z; As[ac + 3][ar] = av.w;
    float4 bv = *(const float4*)&Bp[(long)(n0 + ar) * PPX + k0 + ac];
    Bs[ac + 0][ar] = bv.x; Bs[ac + 1][ar] = bv.y;
    Bs[ac + 2][ar] = bv.z; Bs[ac + 3][ar] = bv.w;
    __syncthreads();
    #pragma unroll
    for (int kk = 0; kk < BK; kk++) {
      const float4 a4 = *(const float4*)&As[kk][ty * 4];
      const float4 b4 = *(const float4*)&Bs[kk][tx * 4];
      const float ae[4] = {a4.x, a4.y, a4.z, a4.w};
      const float be[4] = {b4.x, b4.y, b4.z, b4.w};
      #pragma unroll
      for (int i = 0; i < 4; i++)
        #pragma unroll
        for (int j = 0; j < 4; j++)
          acc[i][j] += ae[i] * be[j];
    }
    __syncthreads();
  }
  const float d0 = delta[0];
  #pragma unroll
  for (int i = 0; i < 4; i++) {
    const int m = m0 + ty * 4 + i;
    #pragma unroll
    for (int j = 0; j < 4; j++) {
      const int n = n0 + tx * 4 + j;
      const float val = d0 * acc[i][j] + Fp[(long)m * PPX + n];
      const int y = n / 48, x = n - (n / 48) * 48;
      attn_p[((size_t)(b * 256 + m)) * PADIMG + (y + 1) * 50 + (x + 1)] = f2bf(val);
    }
  }
}

// ---------------------------------------------------------------------------
// Conv3x3 + BN + ReLU via MFMA bf16, 9-tap decomposition over padded images.
// Block: 128 threads (2 waves). Tile: 64 Cout x 128 pixels. KC=32 chans/slice.
// Wave tile 64x64 => 16 MFMA(16x16x32) per 8 ds_read_b128 (m97-balanced).
// ---------------------------------------------------------------------------
template<bool OUT_BF16>
__global__ __launch_bounds__(128) void conv_mfma(
    const unsigned short* __restrict__ act_p, int Cin,
    const unsigned short* __restrict__ wr,
    const float* __restrict__ gamma, const float* __restrict__ beta,
    const float* __restrict__ mean,  const float* __restrict__ var,
    void* __restrict__ outv)
{
  const int t  = threadIdx.x;
  const int wv = t >> 6;          // wave 0/1
  const int ln = t & 63;
  const int lm = ln & 15;         // MFMA row/col lane index
  const int lk = (ln >> 4) * 8;   // k-offset within 32

  const int bx = blockIdx.x;      // 144 = 8 images * 18 pixel-tiles
  const int bb = bx / 18;
  const int p0 = (bx % 18) * 128;
  const int m0 = blockIdx.y * 64;

  __shared__ __align__(16) unsigned short Bs[256 * 40];   // [i][c], stride 40
  __shared__ __align__(16) unsigned short As[3 * 64 * 40];// [kx][m][c], stride 40

  // padded-coord bases: q(p) = (p/48+1)*50 + (p%48+1) = p + 2*(p/48) + 51
  const int qbase_al = (p0 + 2 * (p0 / 48)) & ~7;   // q(p0)-51, aligned down to 8
  int qoff[4];
  #pragma unroll
  for (int tj = 0; tj < 4; tj++) {
    const int p = p0 + wv * 64 + tj * 16 + lm;
    qoff[tj] = p + 2 * (p / 48) + 51 - qbase_al;
  }

  f4_t acc[4][4];
  #pragma unroll
  for (int i = 0; i < 4; i++)
    #pragma unroll
    for (int j = 0; j < 4; j++) acc[i][j] = (f4_t){0.f, 0.f, 0.f, 0.f};

  for (int c0 = 0; c0 < Cin; c0 += 32) {
    __syncthreads();   // previous slice's readers done before Bs overwrite
    // ---- stage B: 256 padded positions x 32 channels (transposed [i][c]) ----
    const unsigned short* gb = act_p + ((size_t)(bb * Cin + c0)) * PADIMG + qbase_al;
    #pragma unroll
    for (int it = 0; it < 16; it++) {
      const int id = it * 128 + t;
      const int c  = id & 31;
      const int i0 = (id >> 5) * 4;
      const uint2 d = *(const uint2*)(gb + (size_t)c * PADIMG + i0);
      const int base = i0 * 40 + c;
      Bs[base +   0] = (unsigned short)(d.x & 0xffffu);
      Bs[base +  40] = (unsigned short)(d.x >> 16);
      Bs[base +  80] = (unsigned short)(d.y & 0xffffu);
      Bs[base + 120] = (unsigned short)(d.y >> 16);
    }
    for (int ky = 0; ky < 3; ky++) {
      __syncthreads();  // prev tap-group's A readers done (and Bs ready at ky=0)
      // ---- stage A: 3 taps (kx=0..2), 64 rows x 32 chans each ----
      #pragma unroll
      for (int it = 0; it < 6; it++) {
        const int id = it * 128 + t;
        const int tapi = id >> 8;
        const int rid  = id & 255;
        const int m = rid >> 2, kc = rid & 3;
        const uint4 d = *(const uint4*)(wr +
            ((size_t)((ky * 3 + tapi) * 256 + m0 + m)) * Cin + c0 + kc * 8);
        *(uint4*)(As + tapi * 2560 + m * 40 + kc * 8) = d;
      }
      __syncthreads();
      #pragma unroll
      for (int kx = 0; kx < 3; kx++) {
        const int off = (ky - 1) * 50 + (kx - 1);
        short8_t a[4], b[4];
        const unsigned short* Ab = As + kx * 2560;
        #pragma unroll
        for (int ti = 0; ti < 4; ti++)
          a[ti] = *(const short8_t*)(Ab + (ti * 16 + lm) * 40 + lk);
        #pragma unroll
        for (int tj = 0; tj < 4; tj++)
          b[tj] = *(const short8_t*)(Bs + (qoff[tj] + off) * 40 + lk);
        #pragma unroll
        for (int ti = 0; ti < 4; ti++)
          #pragma unroll
          for (int tj = 0; tj < 4; tj++)
            acc[ti][tj] = __builtin_amdgcn_mfma_f32_16x16x32_bf16(
                a[ti], b[tj], acc[ti][tj], 0, 0, 0);
      }
    }
  }

  // ---- epilogue: BN + ReLU, C/D layout col=lane&15, row=(lane>>4)*4+reg ----
  #pragma unroll
  for (int ti = 0; ti < 4; ti++) {
    #pragma unroll
    for (int r = 0; r < 4; r++) {
      const int m = m0 + ti * 16 + ((ln >> 4) << 2) + r;
      const float inv = gamma[m] * rsqrtf(var[m] + 1e-5f);
      const float add = beta[m] - mean[m] * inv;
      const size_t rowb = ((size_t)(bb * 256 + m)) * PPX + p0;
      #pragma unroll
      for (int tj = 0; tj < 4; tj++) {
        const int n = wv * 64 + tj * 16 + lm;
        const float v = relu_(acc[ti][tj][r] * inv + add);
        if (OUT_BF16) ((unsigned short*)outv)[rowb + n] = f2bf(v);
        else          ((float*)outv)[rowb + n] = v;
      }
    }
  }
}

// ---------------------------------------------------------------------------
// pool3(avg/max) * sigmoid(act1) -> padded bf16 cat image [B][512][50*50]
// ---------------------------------------------------------------------------
__global__ __launch_bounds__(256) void pool_gate_cat(
    const float* __restrict__ ftr, const unsigned short* __restrict__ act1b,
    unsigned short* __restrict__ cat_p)
{
  const int idx = blockIdx.x * 256 + threadIdx.x;   // < NTOT
  const int p  = idx % PPX;
  const int bc = idx / PPX;
  const int y = p / 48, x = p - (p / 48) * 48;
  const float* base = ftr + (long)bc * PPX;
  float s = 0.f, mx = -1e30f;
  #pragma unroll
  for (int dy = -1; dy <= 1; dy++) {
    const int yy = y + dy;
    if (yy < 0 || yy >= 48) continue;
    #pragma unroll
    for (int dx = -1; dx <= 1; dx++) {
      const int xx = x + dx;
      if (xx < 0 || xx >= 48) continue;
      const float f = base[yy * 48 + xx];
      s += f; mx = fmaxf(mx, f);
    }
  }
  const float g = bf2f(act1b[idx]);
  const float gate = 1.f / (1.f + expf(-g));
  const int b = bc >> 8, c = bc & 255;
  const size_t pp = (size_t)(y + 1) * 50 + (x + 1);
  const size_t o1 = ((size_t)(b * 512 + c)) * PADIMG + pp;
  cat_p[o1] = f2bf(mx * gate);                                  // max half
  cat_p[o1 + (size_t)256 * PADIMG] = f2bf(s * (1.f / 9.f) * gate); // avg half
}

// ---------------------------------------------------------------------------
extern "C" void kernel_launch(void* const* d_in, const int* in_sizes, int n_in,
                              void* d_out, int out_size, void* d_ws, size_t ws_size,
                              hipStream_t stream)
{
  const float* ftr  = (const float*)d_in[0];
  const float* wq   = (const float*)d_in[1];
  const float* bq   = (const float*)d_in[2];
  const float* wk   = (const float*)d_in[3];
  const float* bk   = (const float*)d_in[4];
  const float* wv   = (const float*)d_in[5];
  const float* bv   = (const float*)d_in[6];
  const float* delta= (const float*)d_in[7];
  const float* w1   = (const float*)d_in[8];
  const float* g1   = (const float*)d_in[9];
  const float* b1   = (const float*)d_in[10];
  const float* m1   = (const float*)d_in[11];
  const float* v1   = (const float*)d_in[12];
  const float* w2   = (const float*)d_in[13];
  const float* g2   = (const float*)d_in[14];
  const float* b2   = (const float*)d_in[15];
  const float* m2   = (const float*)d_in[16];
  const float* v2   = (const float*)d_in[17];
  float* out = (float*)d_out;
  float* ws  = (float*)d_ws;

  float* q  = ws;
  float* kb = ws + (long)NTOT;
  float* vb = ws + 2L * NTOT;
  float* sc = ws + 3L * NTOT;

  const size_t ATTN_P_SH = (size_t)NB * 256 * PADIMG;   // 5,120,000 shorts
  const size_t CAT_P_SH  = (size_t)NB * 512 * PADIMG;   // 10,240,000 shorts
  const size_t ACT1_SH   = (size_t)NTOT;                // 4,718,592 shorts
  const size_t WR1_SH    = (size_t)9 * 256 * 256;       // 589,824 shorts
  const size_t WR2_SH    = (size_t)9 * 256 * 512;       // 1,179,648 shorts

  const size_t needA = ((size_t)3 * NTOT + (size_t)NB * PSQ
                        + (WR1_SH + WR2_SH) / 2) * 4;   // ~230.0 MB
  const bool modeA = ws_size >= needA;

  unsigned short *attn_p, *cat_p, *act1b, *wr1, *wr2;
  if (modeA) {
    float* wrb = sc + (size_t)NB * PSQ;
    wr1    = (unsigned short*)wrb;
    wr2    = wr1 + WR1_SH;
    attn_p = (unsigned short*)q;    // q dead after scores
    act1b  = (unsigned short*)kb;   // kb dead after scores
    cat_p  = (unsigned short*)vb;   // vb+sc dead after PV
  } else {
    float* tail = sc + (size_t)PSQ;
    wr1    = (unsigned short*)tail;
    wr2    = wr1 + WR1_SH;
    attn_p = wr2 + WR2_SH;
    cat_p  = attn_p + ATTN_P_SH;
    act1b  = cat_p + CAT_P_SH;
  }

  dim3 blk(16, 16);

  // weight repacks (independent of activations)
  repack_w<<<dim3((9 * 256 * 256 + 255) / 256), 256, 0, stream>>>(w1, wr1, 256);
  repack_w<<<dim3((9 * 256 * 512 + 255) / 256), 256, 0, stream>>>(w2, wr2, 512);

  // QKV
  gemm_qkv<<<dim3(36, 4, 8), blk, 0, stream>>>(wq, bq, ftr, q);
  gemm_qkv<<<dim3(36, 4, 8), blk, 0, stream>>>(wk, bk, ftr, kb);
  gemm_qkv<<<dim3(36, 4, 8), blk, 0, stream>>>(wv, bv, ftr, vb);

  if (modeA) {
    gemm_scores<<<dim3(36, 36, 8), blk, 0, stream>>>(kb, q, sc, (long)PSQ, 0);
    softmax_rows<<<dim3(PPX, 8), 256, 0, stream>>>(sc, (long)PSQ);
    // q/kb now dead -> zero padded attn image (borders), then PV fills interior
    hipMemsetAsync(attn_p, 0, ATTN_P_SH * 2, stream);
    gemm_pv<<<dim3(36, 4, 8), blk, 0, stream>>>(vb, sc, (long)PSQ, ftr, delta, attn_p, 0);
  } else {
    hipMemsetAsync(attn_p, 0, ATTN_P_SH * 2, stream);
    for (int b = 0; b < NB; b++) {
      gemm_scores<<<dim3(36, 36, 1), blk, 0, stream>>>(kb, q, sc, 0L, b);
      softmax_rows<<<dim3(PPX, 1), 256, 0, stream>>>(sc, 0L);
      gemm_pv<<<dim3(36, 4, 1), blk, 0, stream>>>(vb, sc, 0L, ftr, delta, attn_p, b);
    }
  }

  // conv1 + BN + ReLU (MFMA) -> bf16 act1b
  conv_mfma<true><<<dim3(144, 4), 128, 0, stream>>>(
      attn_p, 256, wr1, g1, b1, m1, v1, (void*)act1b);

  // pool + gate + concat -> padded bf16 cat image
  hipMemsetAsync(cat_p, 0, CAT_P_SH * 2, stream);
  pool_gate_cat<<<dim3(NTOT / 256), 256, 0, stream>>>(ftr, act1b, cat_p);

  // conv2 + BN + ReLU (MFMA) -> fp32 d_out
  conv_mfma<false><<<dim3(144, 4), 128, 0, stream>>>(
      cat_p, 512, wr2, g2, b2, m2, v2, (void*)out);
}

// Round 3
// 613.092 us; speedup vs baseline: 3.4727x; 1.7987x over previous
//
#include <hip/hip_runtime.h>
#include <math.h>

// Problem constants
#define NB   8
#define CCH  256
#define PPX  2304            // 48*48
#define CPb  (CCH*PPX)       // per-batch C*P = 589824
#define NTOT (NB*CPb)        // 4718592
#define PSQ  (PPX*PPX)       // 5308416
#define PADIMG 2500          // 50*50 padded image

typedef short short8_t __attribute__((ext_vector_type(8)));
typedef float f4_t __attribute__((ext_vector_type(4)));

__device__ __forceinline__ float relu_(float x){ return x > 0.f ? x : 0.f; }

__device__ __forceinline__ unsigned short f2bf(float f) {
  unsigned int u = __builtin_bit_cast(unsigned int, f);
  u += 0x7fffu + ((u >> 16) & 1u);
  return (unsigned short)(u >> 16);
}
__device__ __forceinline__ float bf2f(unsigned short h) {
  unsigned int u = ((unsigned int)h) << 16;
  return __builtin_bit_cast(float, u);
}
__device__ __forceinline__ unsigned int pack2(float a, float b) {
  return (unsigned int)f2bf(a) | ((unsigned int)f2bf(b) << 16);
}

// ---------------------------------------------------------------------------
// small casts / repacks
// ---------------------------------------------------------------------------
__global__ __launch_bounds__(256) void castw(
    const float* __restrict__ w, unsigned short* __restrict__ o, int n)
{
  const int i = blockIdx.x * 256 + threadIdx.x;
  if (i < n) o[i] = f2bf(w[i]);
}

__global__ __launch_bounds__(256) void repack_w(
    const float* __restrict__ w, unsigned short* __restrict__ wr, int Cin)
{
  const int idx = blockIdx.x * 256 + threadIdx.x;
  const int total = 9 * 256 * Cin;
  if (idx >= total) return;
  const int c = idx % Cin;
  const int rest = idx / Cin;
  const int o = rest % 256;
  const int tap = rest / 256;
  wr[idx] = f2bf(w[((size_t)o * Cin + c) * 9 + tap]);
}

// ftr [b][c][p] fp32 -> x_t [b][p][c] bf16
__global__ __launch_bounds__(256) void transpose_cast(
    const float* __restrict__ ftr, unsigned short* __restrict__ xt)
{
  const int p0 = blockIdx.x * 64, c0 = blockIdx.y * 64, b = blockIdx.z;
  const int t = threadIdx.x;
  __shared__ unsigned short T[64][72];
  #pragma unroll
  for (int pass = 0; pass < 4; pass++) {
    const int cr = pass * 16 + (t >> 4);
    const int pc = (t & 15) * 4;
    float4 v = *(const float4*)&ftr[((size_t)(b * 256 + c0 + cr)) * PPX + p0 + pc];
    T[pc + 0][cr] = f2bf(v.x); T[pc + 1][cr] = f2bf(v.y);
    T[pc + 2][cr] = f2bf(v.z); T[pc + 3][cr] = f2bf(v.w);
  }
  __syncthreads();
  #pragma unroll
  for (int pass = 0; pass < 2; pass++) {
    const int pr = pass * 32 + (t >> 3);
    const int cc = (t & 7) * 8;
    *(uint4*)&xt[((size_t)(b * PPX + p0 + pr)) * 256 + c0 + cc] = *(const uint4*)&T[pr][cc];
  }
}

// ---------------------------------------------------------------------------
// Generic bf16 MFMA GEMM: O[n][m] = sum_k A[m][k]*B[n][k]   (K=256)
// Tile 128x128, 4 waves (2x2 of 64x64). BIAS: 0 none, 1 on m, 2 on n.
// ---------------------------------------------------------------------------
template<int BIAS>
__global__ __launch_bounds__(256) void gemm_nt(
    const unsigned short* __restrict__ A, long Ab,
    const unsigned short* __restrict__ B, long Bb,
    unsigned short* __restrict__ O, long Ob, int ldo,
    const float* __restrict__ bias)
{
  const int K = 256;
  const int t = threadIdx.x;
  const int ln = t & 63;
  const int wid = t >> 6;
  const int wm = (wid & 1) * 64, wn = (wid >> 1) * 64;
  const int lm = ln & 15, lk = (ln >> 4) * 8;
  const int m0 = blockIdx.x * 128, n0 = blockIdx.y * 128;
  const long bz = blockIdx.z;
  const unsigned short* Ap = A + bz * Ab;
  const unsigned short* Bp = B + bz * Bb;

  __shared__ __align__(16) unsigned short As[128 * 40];
  __shared__ __align__(16) unsigned short Bs[128 * 40];

  f4_t acc[4][4];
  #pragma unroll
  for (int i = 0; i < 4; i++)
    #pragma unroll
    for (int j = 0; j < 4; j++) acc[i][j] = (f4_t){0.f, 0.f, 0.f, 0.f};

  for (int k0 = 0; k0 < K; k0 += 32) {
    __syncthreads();
    #pragma unroll
    for (int it = 0; it < 2; it++) {
      const int id = it * 256 + t;
      const int r = id >> 2, c4 = (id & 3) * 8;
      *(uint4*)(As + r * 40 + c4) = *(const uint4*)(Ap + (size_t)(m0 + r) * K + k0 + c4);
      *(uint4*)(Bs + r * 40 + c4) = *(const uint4*)(Bp + (size_t)(n0 + r) * K + k0 + c4);
    }
    __syncthreads();
    short8_t a[4], b[4];
    #pragma unroll
    for (int ti = 0; ti < 4; ti++)
      a[ti] = *(const short8_t*)(As + (wm + ti * 16 + lm) * 40 + lk);
    #pragma unroll
    for (int tj = 0; tj < 4; tj++)
      b[tj] = *(const short8_t*)(Bs + (wn + tj * 16 + lm) * 40 + lk);
    #pragma unroll
    for (int ti = 0; ti < 4; ti++)
      #pragma unroll
      for (int tj = 0; tj < 4; tj++)
        acc[ti][tj] = __builtin_amdgcn_mfma_f32_16x16x32_bf16(
            a[ti], b[tj], acc[ti][tj], 0, 0, 0);
  }
  #pragma unroll
  for (int ti = 0; ti < 4; ti++) {
    const int mb = m0 + wm + ti * 16 + ((ln >> 4) << 2);
    #pragma unroll
    for (int tj = 0; tj < 4; tj++) {
      const int n = n0 + wn + tj * 16 + lm;
      float add0 = 0.f, add1 = 0.f, add2 = 0.f, add3 = 0.f;
      if (BIAS == 1) { add0 = bias[mb]; add1 = bias[mb+1]; add2 = bias[mb+2]; add3 = bias[mb+3]; }
      if (BIAS == 2) { add0 = add1 = add2 = add3 = bias[n]; }
      uint2 o;
      o.x = pack2(acc[ti][tj][0] + add0, acc[ti][tj][1] + add1);
      o.y = pack2(acc[ti][tj][2] + add2, acc[ti][tj][3] + add3);
      *(uint2*)(O + bz * Ob + (size_t)n * ldo + mb) = o;
    }
  }
}

// ---------------------------------------------------------------------------
// Row stats of St: mx[j] = max_i St[j][i], il[j] = 1/sum_i exp(St-mx)
// ---------------------------------------------------------------------------
__global__ __launch_bounds__(256) void rowstats(
    const unsigned short* __restrict__ St, long sstride,
    float* __restrict__ mx, float* __restrict__ il, int bstart)
{
  const int j = blockIdx.x, bb = blockIdx.y;
  const unsigned short* row = St + (long)bb * sstride + (size_t)j * PPX;
  const int t = threadIdx.x;

  float v[16];
  int nv = 0;
  float m = -1e30f;
  for (int ch = t; ch < 288; ch += 256) {
    const uint4 d = *(const uint4*)(row + ch * 8);
    const unsigned int* dp = (const unsigned int*)&d;
    #pragma unroll
    for (int q = 0; q < 4; q++) {
      v[nv]     = bf2f((unsigned short)(dp[q] & 0xffffu));
      v[nv + 1] = bf2f((unsigned short)(dp[q] >> 16));
      m = fmaxf(m, fmaxf(v[nv], v[nv + 1]));
      nv += 2;
    }
  }
  __shared__ float red[256];
  red[t] = m; __syncthreads();
  for (int s = 128; s > 0; s >>= 1) {
    if (t < s) red[t] = fmaxf(red[t], red[t + s]);
    __syncthreads();
  }
  m = red[0]; __syncthreads();
  float sum = 0.f;
  for (int u = 0; u < nv; u++) sum += expf(v[u] - m);
  red[t] = sum; __syncthreads();
  for (int s = 128; s > 0; s >>= 1) {
    if (t < s) red[t] += red[t + s];
    __syncthreads();
  }
  if (t == 0) {
    mx[(size_t)(bstart + bb) * PPX + j] = m;
    il[(size_t)(bstart + bb) * PPX + j] = 1.f / red[0];
  }
}

// ---------------------------------------------------------------------------
// PV: attn[c,j] = delta * sum_i v[c,i]*softmax_w[i,j] + ftr[c,j]
// exp fused into B-staging. Tile 128c x 64j, 2 waves. K=2304 (i).
// -> writes padded bf16 attn image
// ---------------------------------------------------------------------------
__global__ __launch_bounds__(128) void pv_mfma(
    const unsigned short* __restrict__ vbuf, const unsigned short* __restrict__ St,
    long sstride, const float* __restrict__ mx, const float* __restrict__ il,
    const float* __restrict__ ftr, const float* __restrict__ delta,
    unsigned short* __restrict__ attn_p, int bstart)
{
  const int t = threadIdx.x, w = t >> 6, ln = t & 63;
  const int lm = ln & 15, lk = (ln >> 4) * 8;
  const int m0 = blockIdx.x * 128;
  const int j0 = blockIdx.y * 64;
  const int b  = bstart + blockIdx.z;
  const unsigned short* Stb = St + (long)blockIdx.z * sstride;
  const float* mxb = mx + (size_t)b * PPX;
  const float* ilb = il + (size_t)b * PPX;

  __shared__ __align__(16) unsigned short As[128 * 40];
  __shared__ __align__(16) unsigned short Bs[64 * 40];

  f4_t acc[4][4];
  #pragma unroll
  for (int i = 0; i < 4; i++)
    #pragma unroll
    for (int j = 0; j < 4; j++) acc[i][j] = (f4_t){0.f, 0.f, 0.f, 0.f};

  for (int i0 = 0; i0 < PPX; i0 += 32) {
    __syncthreads();
    #pragma unroll
    for (int it = 0; it < 4; it++) {
      const int id = it * 128 + t;
      const int r = id >> 2, c4 = (id & 3) * 8;
      *(uint4*)(As + r * 40 + c4) =
          *(const uint4*)(vbuf + ((size_t)(b * 256 + m0 + r)) * PPX + i0 + c4);
    }
    #pragma unroll
    for (int it = 0; it < 2; it++) {
      const int id = it * 128 + t;
      const int jr = id >> 2, c4 = (id & 3) * 8;
      const uint4 d = *(const uint4*)(Stb + (size_t)(j0 + jr) * PPX + i0 + c4);
      const float mj = mxb[j0 + jr], sj = ilb[j0 + jr];
      const unsigned int* dp = (const unsigned int*)&d;
      unsigned int res[4];
      #pragma unroll
      for (int q = 0; q < 4; q++) {
        const float lo = expf(bf2f((unsigned short)(dp[q] & 0xffffu)) - mj) * sj;
        const float hi = expf(bf2f((unsigned short)(dp[q] >> 16)) - mj) * sj;
        res[q] = pack2(lo, hi);
      }
      *(uint4*)(Bs + jr * 40 + c4) = *(const uint4*)res;
    }
    __syncthreads();
    short8_t a[4], bfr[4];
    #pragma unroll
    for (int ti = 0; ti < 4; ti++)
      a[ti] = *(const short8_t*)(As + (w * 64 + ti * 16 + lm) * 40 + lk);
    #pragma unroll
    for (int tj = 0; tj < 4; tj++)
      bfr[tj] = *(const short8_t*)(Bs + (tj * 16 + lm) * 40 + lk);
    #pragma unroll
    for (int ti = 0; ti < 4; ti++)
      #pragma unroll
      for (int tj = 0; tj < 4; tj++)
        acc[ti][tj] = __builtin_amdgcn_mfma_f32_16x16x32_bf16(
            a[ti], bfr[tj], acc[ti][tj], 0, 0, 0);
  }
  const float d0 = delta[0];
  #pragma unroll
  for (int ti = 0; ti < 4; ti++) {
    #pragma unroll
    for (int r = 0; r < 4; r++) {
      const int m = m0 + w * 64 + ti * 16 + ((ln >> 4) << 2) + r;
      const size_t rowf = ((size_t)(b * 256 + m)) * PPX;
      const size_t rowp = ((size_t)(b * 256 + m)) * PADIMG;
      #pragma unroll
      for (int tj = 0; tj < 4; tj++) {
        const int n = j0 + tj * 16 + lm;
        const float val = d0 * acc[ti][tj][r] + ftr[rowf + n];
        const int y = n / 48, x = n - (n / 48) * 48;
        attn_p[rowp + (y + 1) * 50 + (x + 1)] = f2bf(val);
      }
    }
  }
}

// ---------------------------------------------------------------------------
// Conv3x3 + BN + ReLU via MFMA bf16 (unchanged from round 2 — validated)
// ---------------------------------------------------------------------------
template<bool OUT_BF16>
__global__ __launch_bounds__(128) void conv_mfma(
    const unsigned short* __restrict__ act_p, int Cin,
    const unsigned short* __restrict__ wr,
    const float* __restrict__ gamma, const float* __restrict__ beta,
    const float* __restrict__ mean,  const float* __restrict__ var,
    void* __restrict__ outv)
{
  const int t  = threadIdx.x;
  const int wv = t >> 6;
  const int ln = t & 63;
  const int lm = ln & 15;
  const int lk = (ln >> 4) * 8;

  const int bx = blockIdx.x;
  const int bb = bx / 18;
  const int p0 = (bx % 18) * 128;
  const int m0 = blockIdx.y * 64;

  __shared__ __align__(16) unsigned short Bs[256 * 40];
  __shared__ __align__(16) unsigned short As[3 * 64 * 40];

  const int qbase_al = (p0 + 2 * (p0 / 48)) & ~7;
  int qoff[4];
  #pragma unroll
  for (int tj = 0; tj < 4; tj++) {
    const int p = p0 + wv * 64 + tj * 16 + lm;
    qoff[tj] = p + 2 * (p / 48) + 51 - qbase_al;
  }

  f4_t acc[4][4];
  #pragma unroll
  for (int i = 0; i < 4; i++)
    #pragma unroll
    for (int j = 0; j < 4; j++) acc[i][j] = (f4_t){0.f, 0.f, 0.f, 0.f};

  for (int c0 = 0; c0 < Cin; c0 += 32) {
    __syncthreads();
    const unsigned short* gb = act_p + ((size_t)(bb * Cin + c0)) * PADIMG + qbase_al;
    #pragma unroll
    for (int it = 0; it < 16; it++) {
      const int id = it * 128 + t;
      const int c  = id & 31;
      const int i0 = (id >> 5) * 4;
      const uint2 d = *(const uint2*)(gb + (size_t)c * PADIMG + i0);
      const int base = i0 * 40 + c;
      Bs[base +   0] = (unsigned short)(d.x & 0xffffu);
      Bs[base +  40] = (unsigned short)(d.x >> 16);
      Bs[base +  80] = (unsigned short)(d.y & 0xffffu);
      Bs[base + 120] = (unsigned short)(d.y >> 16);
    }
    for (int ky = 0; ky < 3; ky++) {
      __syncthreads();
      #pragma unroll
      for (int it = 0; it < 6; it++) {
        const int id = it * 128 + t;
        const int tapi = id >> 8;
        const int rid  = id & 255;
        const int m = rid >> 2, kc = rid & 3;
        const uint4 d = *(const uint4*)(wr +
            ((size_t)((ky * 3 + tapi) * 256 + m0 + m)) * Cin + c0 + kc * 8);
        *(uint4*)(As + tapi * 2560 + m * 40 + kc * 8) = d;
      }
      __syncthreads();
      #pragma unroll
      for (int kx = 0; kx < 3; kx++) {
        const int off = (ky - 1) * 50 + (kx - 1);
        short8_t a[4], b[4];
        const unsigned short* Ab = As + kx * 2560;
        #pragma unroll
        for (int ti = 0; ti < 4; ti++)
          a[ti] = *(const short8_t*)(Ab + (ti * 16 + lm) * 40 + lk);
        #pragma unroll
        for (int tj = 0; tj < 4; tj++)
          b[tj] = *(const short8_t*)(Bs + (qoff[tj] + off) * 40 + lk);
        #pragma unroll
        for (int ti = 0; ti < 4; ti++)
          #pragma unroll
          for (int tj = 0; tj < 4; tj++)
            acc[ti][tj] = __builtin_amdgcn_mfma_f32_16x16x32_bf16(
                a[ti], b[tj], acc[ti][tj], 0, 0, 0);
      }
    }
  }

  #pragma unroll
  for (int ti = 0; ti < 4; ti++) {
    #pragma unroll
    for (int r = 0; r < 4; r++) {
      const int m = m0 + ti * 16 + ((ln >> 4) << 2) + r;
      const float inv = gamma[m] * rsqrtf(var[m] + 1e-5f);
      const float add = beta[m] - mean[m] * inv;
      const size_t rowb = ((size_t)(bb * 256 + m)) * PPX + p0;
      #pragma unroll
      for (int tj = 0; tj < 4; tj++) {
        const int n = wv * 64 + tj * 16 + lm;
        const float v = relu_(acc[ti][tj][r] * inv + add);
        if (OUT_BF16) ((unsigned short*)outv)[rowb + n] = f2bf(v);
        else          ((float*)outv)[rowb + n] = v;
      }
    }
  }
}

// ---------------------------------------------------------------------------
// pool3(avg/max) * sigmoid(act1) -> padded bf16 cat image (unchanged)
// ---------------------------------------------------------------------------
__global__ __launch_bounds__(256) void pool_gate_cat(
    const float* __restrict__ ftr, const unsigned short* __restrict__ act1b,
    unsigned short* __restrict__ cat_p)
{
  const int idx = blockIdx.x * 256 + threadIdx.x;
  const int p  = idx % PPX;
  const int bc = idx / PPX;
  const int y = p / 48, x = p - (p / 48) * 48;
  const float* base = ftr + (long)bc * PPX;
  float s = 0.f, mxv = -1e30f;
  #pragma unroll
  for (int dy = -1; dy <= 1; dy++) {
    const int yy = y + dy;
    if (yy < 0 || yy >= 48) continue;
    #pragma unroll
    for (int dx = -1; dx <= 1; dx++) {
      const int xx = x + dx;
      if (xx < 0 || xx >= 48) continue;
      const float f = base[yy * 48 + xx];
      s += f; mxv = fmaxf(mxv, f);
    }
  }
  const float g = bf2f(act1b[idx]);
  const float gate = 1.f / (1.f + expf(-g));
  const int b = bc >> 8, c = bc & 255;
  const size_t pp = (size_t)(y + 1) * 50 + (x + 1);
  const size_t o1 = ((size_t)(b * 512 + c)) * PADIMG + pp;
  cat_p[o1] = f2bf(mxv * gate);
  cat_p[o1 + (size_t)256 * PADIMG] = f2bf(s * (1.f / 9.f) * gate);
}

// ---------------------------------------------------------------------------
extern "C" void kernel_launch(void* const* d_in, const int* in_sizes, int n_in,
                              void* d_out, int out_size, void* d_ws, size_t ws_size,
                              hipStream_t stream)
{
  const float* ftr  = (const float*)d_in[0];
  const float* wq   = (const float*)d_in[1];
  const float* bq   = (const float*)d_in[2];
  const float* wk   = (const float*)d_in[3];
  const float* bk   = (const float*)d_in[4];
  const float* wv   = (const float*)d_in[5];
  const float* bv   = (const float*)d_in[6];
  const float* delta= (const float*)d_in[7];
  const float* w1   = (const float*)d_in[8];
  const float* g1   = (const float*)d_in[9];
  const float* b1   = (const float*)d_in[10];
  const float* m1   = (const float*)d_in[11];
  const float* v1   = (const float*)d_in[12];
  const float* w2   = (const float*)d_in[13];
  const float* g2   = (const float*)d_in[14];
  const float* b2   = (const float*)d_in[15];
  const float* m2   = (const float*)d_in[16];
  const float* v2   = (const float*)d_in[17];
  float* out = (float*)d_out;

  // ---- workspace layout (shorts) ----
  const size_t XT  = (size_t)NTOT;          // 4,718,592 per bf16 tensor
  unsigned short* base = (unsigned short*)d_ws;
  unsigned short* xt   = base;
  unsigned short* qt   = xt  + XT;
  unsigned short* kt   = qt  + XT;
  unsigned short* vbuf = kt  + XT;
  unsigned short* wqb  = vbuf + XT;
  unsigned short* wkb  = wqb + 65536;
  unsigned short* wvb  = wkb + 65536;
  unsigned short* wr1  = wvb + 65536;
  unsigned short* wr2  = wr1 + (size_t)9 * 256 * 256;
  unsigned short* attn_p = wr2 + (size_t)9 * 256 * 512;
  unsigned short* act1b  = attn_p + (size_t)NB * 256 * PADIMG;
  unsigned short* cat_p  = act1b + XT;
  float* mx = (float*)(cat_p + (size_t)NB * 512 * PADIMG);
  float* il = mx + (size_t)NB * PPX;
  unsigned short* St = (unsigned short*)(il + (size_t)NB * PPX);

  const size_t head_bytes = (size_t)((char*)St - (char*)base);
  const bool modeA = ws_size >= head_bytes + (size_t)NB * PSQ * 2;

  const size_t ATTN_P_SH = (size_t)NB * 256 * PADIMG;
  const size_t CAT_P_SH  = (size_t)NB * 512 * PADIMG;

  // ---- weight preps ----
  castw<<<dim3(256), 256, 0, stream>>>(wq, wqb, 65536);
  castw<<<dim3(256), 256, 0, stream>>>(wk, wkb, 65536);
  castw<<<dim3(256), 256, 0, stream>>>(wv, wvb, 65536);
  repack_w<<<dim3((9 * 256 * 256 + 255) / 256), 256, 0, stream>>>(w1, wr1, 256);
  repack_w<<<dim3((9 * 256 * 512 + 255) / 256), 256, 0, stream>>>(w2, wr2, 512);

  // ---- x transpose ----
  transpose_cast<<<dim3(36, 4, 8), 256, 0, stream>>>(ftr, xt);

  // ---- QKV ----
  // q_t[p][c], k_t[p][c]: A=W[m=co][k=ci], B=x_t[n=p][k=ci]
  gemm_nt<1><<<dim3(2, 18, 8), 256, 0, stream>>>(wqb, 0L, xt, (long)CPb, qt, (long)CPb, 256, bq);
  gemm_nt<1><<<dim3(2, 18, 8), 256, 0, stream>>>(wkb, 0L, xt, (long)CPb, kt, (long)CPb, 256, bk);
  // v[c][p]: A=x_t[m=p][k=ci], B=W[n=co][k=ci]
  gemm_nt<2><<<dim3(18, 2, 8), 256, 0, stream>>>(xt, (long)CPb, wvb, 0L, vbuf, (long)CPb, PPX, bv);

  hipMemsetAsync(attn_p, 0, ATTN_P_SH * 2, stream);

  if (modeA) {
    // St[j][i]: A=q_t[m=i][k=c], B=k_t[n=j][k=c]
    gemm_nt<0><<<dim3(18, 18, 8), 256, 0, stream>>>(qt, (long)CPb, kt, (long)CPb,
                                                    St, (long)PSQ, PPX, nullptr);
    rowstats<<<dim3(PPX, 8), 256, 0, stream>>>(St, (long)PSQ, mx, il, 0);
    pv_mfma<<<dim3(2, 36, 8), 128, 0, stream>>>(vbuf, St, (long)PSQ, mx, il,
                                                ftr, delta, attn_p, 0);
  } else {
    for (int b = 0; b < NB; b++) {
      gemm_nt<0><<<dim3(18, 18, 1), 256, 0, stream>>>(
          qt + (size_t)b * CPb, 0L, kt + (size_t)b * CPb, 0L, St, 0L, PPX, nullptr);
      rowstats<<<dim3(PPX, 1), 256, 0, stream>>>(St, 0L, mx, il, b);
      pv_mfma<<<dim3(2, 36, 1), 128, 0, stream>>>(vbuf, St, 0L, mx, il,
                                                  ftr, delta, attn_p, b);
    }
  }

  // ---- conv1 + BN + ReLU -> bf16 act1b ----
  conv_mfma<true><<<dim3(144, 4), 128, 0, stream>>>(
      attn_p, 256, wr1, g1, b1, m1, v1, (void*)act1b);

  // ---- pool + gate + concat ----
  hipMemsetAsync(cat_p, 0, CAT_P_SH * 2, stream);
  pool_gate_cat<<<dim3(NTOT / 256), 256, 0, stream>>>(ftr, act1b, cat_p);

  // ---- conv2 + BN + ReLU -> fp32 out ----
  conv_mfma<false><<<dim3(144, 4), 128, 0, stream>>>(
      cat_p, 512, wr2, g2, b2, m2, v2, (void*)out);
}

// Round 4
// 563.925 us; speedup vs baseline: 3.7755x; 1.0872x over previous
//
#include <hip/hip_runtime.h>
#include <math.h>

// Problem constants
#define NB   8
#define CCH  256
#define PPX  2304            // 48*48
#define CPb  (CCH*PPX)       // per-batch C*P = 589824
#define NTOT (NB*CPb)        // 4718592
#define PSQ  (PPX*PPX)       // 5308416
#define PADIMG 2500          // 50*50 padded image

typedef short short8_t __attribute__((ext_vector_type(8)));
typedef float f4_t __attribute__((ext_vector_type(4)));

__device__ __forceinline__ float relu_(float x){ return x > 0.f ? x : 0.f; }

__device__ __forceinline__ unsigned short f2bf(float f) {
  unsigned int u = __builtin_bit_cast(unsigned int, f);
  u += 0x7fffu + ((u >> 16) & 1u);
  return (unsigned short)(u >> 16);
}
__device__ __forceinline__ float bf2f(unsigned short h) {
  unsigned int u = ((unsigned int)h) << 16;
  return __builtin_bit_cast(float, u);
}
__device__ __forceinline__ unsigned int pack2(float a, float b) {
  return (unsigned int)f2bf(a) | ((unsigned int)f2bf(b) << 16);
}

// ---------------------------------------------------------------------------
// small casts / repacks
// ---------------------------------------------------------------------------
__global__ __launch_bounds__(256) void castw(
    const float* __restrict__ w, unsigned short* __restrict__ o, int n)
{
  const int i = blockIdx.x * 256 + threadIdx.x;
  if (i < n) o[i] = f2bf(w[i]);
}

__global__ __launch_bounds__(256) void repack_w(
    const float* __restrict__ w, unsigned short* __restrict__ wr, int Cin)
{
  const int idx = blockIdx.x * 256 + threadIdx.x;
  const int total = 9 * 256 * Cin;
  if (idx >= total) return;
  const int c = idx % Cin;
  const int rest = idx / Cin;
  const int o = rest % 256;
  const int tap = rest / 256;
  wr[idx] = f2bf(w[((size_t)o * Cin + c) * 9 + tap]);
}

// ftr [b][c][p] fp32 -> x_t [b][p][c] bf16
__global__ __launch_bounds__(256) void transpose_cast(
    const float* __restrict__ ftr, unsigned short* __restrict__ xt)
{
  const int p0 = blockIdx.x * 64, c0 = blockIdx.y * 64, b = blockIdx.z;
  const int t = threadIdx.x;
  __shared__ unsigned short T[64][72];
  #pragma unroll
  for (int pass = 0; pass < 4; pass++) {
    const int cr = pass * 16 + (t >> 4);
    const int pc = (t & 15) * 4;
    float4 v = *(const float4*)&ftr[((size_t)(b * 256 + c0 + cr)) * PPX + p0 + pc];
    T[pc + 0][cr] = f2bf(v.x); T[pc + 1][cr] = f2bf(v.y);
    T[pc + 2][cr] = f2bf(v.z); T[pc + 3][cr] = f2bf(v.w);
  }
  __syncthreads();
  #pragma unroll
  for (int pass = 0; pass < 2; pass++) {
    const int pr = pass * 32 + (t >> 3);
    const int cc = (t & 7) * 8;
    *(uint4*)&xt[((size_t)(b * PPX + p0 + pr)) * 256 + c0 + cc] = *(const uint4*)&T[pr][cc];
  }
}

// ---------------------------------------------------------------------------
// Generic bf16 MFMA GEMM: O[n][m] = sum_k A[m][k]*B[n][k]   (K=256)
// Tile 128x128, 4 waves (2x2 of 64x64). BIAS: 0 none, 1 on m, 2 on n.
// ---------------------------------------------------------------------------
template<int BIAS>
__global__ __launch_bounds__(256) void gemm_nt(
    const unsigned short* __restrict__ A, long Ab,
    const unsigned short* __restrict__ B, long Bb,
    unsigned short* __restrict__ O, long Ob, int ldo,
    const float* __restrict__ bias)
{
  const int K = 256;
  const int t = threadIdx.x;
  const int ln = t & 63;
  const int wid = t >> 6;
  const int wm = (wid & 1) * 64, wn = (wid >> 1) * 64;
  const int lm = ln & 15, lk = (ln >> 4) * 8;
  const int m0 = blockIdx.x * 128, n0 = blockIdx.y * 128;
  const long bz = blockIdx.z;
  const unsigned short* Ap = A + bz * Ab;
  const unsigned short* Bp = B + bz * Bb;

  __shared__ __align__(16) unsigned short As[128 * 40];
  __shared__ __align__(16) unsigned short Bs[128 * 40];

  f4_t acc[4][4];
  #pragma unroll
  for (int i = 0; i < 4; i++)
    #pragma unroll
    for (int j = 0; j < 4; j++) acc[i][j] = (f4_t){0.f, 0.f, 0.f, 0.f};

  for (int k0 = 0; k0 < K; k0 += 32) {
    __syncthreads();
    #pragma unroll
    for (int it = 0; it < 2; it++) {
      const int id = it * 256 + t;
      const int r = id >> 2, c4 = (id & 3) * 8;
      *(uint4*)(As + r * 40 + c4) = *(const uint4*)(Ap + (size_t)(m0 + r) * K + k0 + c4);
      *(uint4*)(Bs + r * 40 + c4) = *(const uint4*)(Bp + (size_t)(n0 + r) * K + k0 + c4);
    }
    __syncthreads();
    short8_t a[4], b[4];
    #pragma unroll
    for (int ti = 0; ti < 4; ti++)
      a[ti] = *(const short8_t*)(As + (wm + ti * 16 + lm) * 40 + lk);
    #pragma unroll
    for (int tj = 0; tj < 4; tj++)
      b[tj] = *(const short8_t*)(Bs + (wn + tj * 16 + lm) * 40 + lk);
    #pragma unroll
    for (int ti = 0; ti < 4; ti++)
      #pragma unroll
      for (int tj = 0; tj < 4; tj++)
        acc[ti][tj] = __builtin_amdgcn_mfma_f32_16x16x32_bf16(
            a[ti], b[tj], acc[ti][tj], 0, 0, 0);
  }
  #pragma unroll
  for (int ti = 0; ti < 4; ti++) {
    const int mb = m0 + wm + ti * 16 + ((ln >> 4) << 2);
    #pragma unroll
    for (int tj = 0; tj < 4; tj++) {
      const int n = n0 + wn + tj * 16 + lm;
      float add0 = 0.f, add1 = 0.f, add2 = 0.f, add3 = 0.f;
      if (BIAS == 1) { add0 = bias[mb]; add1 = bias[mb+1]; add2 = bias[mb+2]; add3 = bias[mb+3]; }
      if (BIAS == 2) { add0 = add1 = add2 = add3 = bias[n]; }
      uint2 o;
      o.x = pack2(acc[ti][tj][0] + add0, acc[ti][tj][1] + add1);
      o.y = pack2(acc[ti][tj][2] + add2, acc[ti][tj][3] + add3);
      *(uint2*)(O + bz * Ob + (size_t)n * ldo + mb) = o;
    }
  }
}

// ---------------------------------------------------------------------------
// Row softmax of St IN PLACE: row j: W[i] = exp(s-mx)/sum  (bf16 out)
// ---------------------------------------------------------------------------
__global__ __launch_bounds__(256) void rowstats(
    unsigned short* __restrict__ St, long sstride)
{
  const int j = blockIdx.x, bb = blockIdx.y;
  unsigned short* row = St + (long)bb * sstride + (size_t)j * PPX;
  const int t = threadIdx.x;

  float v[16];
  int nv = 0;
  float m = -1e30f;
  for (int ch = t; ch < 288; ch += 256) {
    const uint4 d = *(const uint4*)(row + ch * 8);
    const unsigned int* dp = (const unsigned int*)&d;
    #pragma unroll
    for (int q = 0; q < 4; q++) {
      v[nv]     = bf2f((unsigned short)(dp[q] & 0xffffu));
      v[nv + 1] = bf2f((unsigned short)(dp[q] >> 16));
      m = fmaxf(m, fmaxf(v[nv], v[nv + 1]));
      nv += 2;
    }
  }
  __shared__ float red[256];
  red[t] = m; __syncthreads();
  for (int s = 128; s > 0; s >>= 1) {
    if (t < s) red[t] = fmaxf(red[t], red[t + s]);
    __syncthreads();
  }
  m = red[0]; __syncthreads();
  float sum = 0.f;
  for (int u = 0; u < nv; u++) { v[u] = expf(v[u] - m); sum += v[u]; }
  red[t] = sum; __syncthreads();
  for (int s = 128; s > 0; s >>= 1) {
    if (t < s) red[t] += red[t + s];
    __syncthreads();
  }
  const float inv = 1.f / red[0];
  int u = 0;
  for (int ch = t; ch < 288; ch += 256) {
    unsigned int res[4];
    #pragma unroll
    for (int q = 0; q < 4; q++) {
      res[q] = pack2(v[u] * inv, v[u + 1] * inv);
      u += 2;
    }
    *(uint4*)(row + ch * 8) = *(const uint4*)res;
  }
}

// ---------------------------------------------------------------------------
// PV: attn[c,j] = delta * sum_i v[c,i]*W[j,i] + ftr[c,j]   (pure bf16 GEMM)
// Tile 128c x 64j, 2 waves. K=2304. -> padded bf16 attn image [pos][chan]
// ---------------------------------------------------------------------------
__global__ __launch_bounds__(128) void pv_mfma(
    const unsigned short* __restrict__ vbuf, const unsigned short* __restrict__ St,
    long sstride, const float* __restrict__ ftr, const float* __restrict__ delta,
    unsigned short* __restrict__ attn_p, int bstart)
{
  const int t = threadIdx.x, w = t >> 6, ln = t & 63;
  const int lm = ln & 15, lk = (ln >> 4) * 8;
  const int m0 = blockIdx.x * 128;
  const int j0 = blockIdx.y * 64;
  const int b  = bstart + blockIdx.z;
  const unsigned short* Stb = St + (long)blockIdx.z * sstride;

  __shared__ __align__(16) unsigned short As[128 * 40];
  __shared__ __align__(16) unsigned short Bs[64 * 40];

  f4_t acc[4][4];
  #pragma unroll
  for (int i = 0; i < 4; i++)
    #pragma unroll
    for (int j = 0; j < 4; j++) acc[i][j] = (f4_t){0.f, 0.f, 0.f, 0.f};

  for (int i0 = 0; i0 < PPX; i0 += 32) {
    __syncthreads();
    #pragma unroll
    for (int it = 0; it < 4; it++) {
      const int id = it * 128 + t;
      const int r = id >> 2, c4 = (id & 3) * 8;
      *(uint4*)(As + r * 40 + c4) =
          *(const uint4*)(vbuf + ((size_t)(b * 256 + m0 + r)) * PPX + i0 + c4);
    }
    #pragma unroll
    for (int it = 0; it < 2; it++) {
      const int id = it * 128 + t;
      const int jr = id >> 2, c4 = (id & 3) * 8;
      *(uint4*)(Bs + jr * 40 + c4) =
          *(const uint4*)(Stb + (size_t)(j0 + jr) * PPX + i0 + c4);
    }
    __syncthreads();
    short8_t a[4], bfr[4];
    #pragma unroll
    for (int ti = 0; ti < 4; ti++)
      a[ti] = *(const short8_t*)(As + (w * 64 + ti * 16 + lm) * 40 + lk);
    #pragma unroll
    for (int tj = 0; tj < 4; tj++)
      bfr[tj] = *(const short8_t*)(Bs + (tj * 16 + lm) * 40 + lk);
    #pragma unroll
    for (int ti = 0; ti < 4; ti++)
      #pragma unroll
      for (int tj = 0; tj < 4; tj++)
        acc[ti][tj] = __builtin_amdgcn_mfma_f32_16x16x32_bf16(
            a[ti], bfr[tj], acc[ti][tj], 0, 0, 0);
  }
  const float d0 = delta[0];
  #pragma unroll
  for (int ti = 0; ti < 4; ti++) {
    const int m = m0 + w * 64 + ti * 16 + ((ln >> 4) << 2);
    #pragma unroll
    for (int tj = 0; tj < 4; tj++) {
      const int n = j0 + tj * 16 + lm;            // pixel
      const int y = n / 48, x = n - (n / 48) * 48;
      const size_t pp = (size_t)(y + 1) * 50 + (x + 1);
      float vr[4];
      #pragma unroll
      for (int r = 0; r < 4; r++)
        vr[r] = d0 * acc[ti][tj][r] + ftr[((size_t)(b * 256 + m + r)) * PPX + n];
      uint2 o;
      o.x = pack2(vr[0], vr[1]);
      o.y = pack2(vr[2], vr[3]);
      *(uint2*)(attn_p + ((size_t)b * PADIMG + pp) * 256 + m) = o;
    }
  }
}

// ---------------------------------------------------------------------------
// Conv3x3 + BN + ReLU, MFMA bf16, [pos][chan] activations.
// Block: 128 thr (2 waves), tile 64 Cout x 128 px. Per 32-chan slice:
// stage B (240 pos x 32c) + A (all 9 taps x 64 x 32c) with 2 barriers,
// then 144 MFMA / 72 ds_read_b128 unrolled.
// ---------------------------------------------------------------------------
template<bool OUT_BF16>
__global__ __launch_bounds__(128) void conv_mfma(
    const unsigned short* __restrict__ act_p, int Cin,
    const unsigned short* __restrict__ wr,
    const float* __restrict__ gamma, const float* __restrict__ beta,
    const float* __restrict__ mean,  const float* __restrict__ var,
    void* __restrict__ outv)
{
  const int t  = threadIdx.x;
  const int wv = t >> 6;
  const int ln = t & 63;
  const int lm = ln & 15;
  const int lk = (ln >> 4) * 8;

  const int bx = blockIdx.x;      // 144 = 8 images * 18 pixel-tiles
  const int bb = bx / 18;
  const int p0 = (bx % 18) * 128;
  const int m0 = blockIdx.y * 64;

  __shared__ __align__(16) unsigned short Bs[240 * 40];    // [pos][c] 19.2 KB
  __shared__ __align__(16) unsigned short As[9 * 64 * 40]; // [tap][m][c] 46 KB

  const int qbase = p0 + 2 * (p0 / 48);    // q(p0) - 51
  int qoff[4];
  #pragma unroll
  for (int tj = 0; tj < 4; tj++) {
    const int p = p0 + wv * 64 + tj * 16 + lm;
    qoff[tj] = (p - p0) + 2 * (p / 48 - p0 / 48) + 51;
  }

  f4_t acc[4][4];
  #pragma unroll
  for (int i = 0; i < 4; i++)
    #pragma unroll
    for (int j = 0; j < 4; j++) acc[i][j] = (f4_t){0.f, 0.f, 0.f, 0.f};

  for (int c0 = 0; c0 < Cin; c0 += 32) {
    __syncthreads();
    // ---- stage B: 240 positions x 32 chans, direct b128 (no transpose) ----
    const unsigned short* gb = act_p + ((size_t)bb * PADIMG + qbase) * Cin + c0;
    #pragma unroll
    for (int it = 0; it < 8; it++) {
      const int id = it * 128 + t;
      if (id < 960) {
        const int r = id >> 2, cq = (id & 3) * 8;
        *(uint4*)(Bs + r * 40 + cq) = *(const uint4*)(gb + (size_t)r * Cin + cq);
      }
    }
    // ---- stage A: all 9 taps x 64 rows x 32 chans ----
    #pragma unroll
    for (int it = 0; it < 18; it++) {
      const int id = it * 128 + t;
      const int tap = id >> 8;
      const int rid = id & 255;
      const int mrow = rid >> 2, cq = (rid & 3) * 8;
      *(uint4*)(As + tap * 2560 + mrow * 40 + cq) =
          *(const uint4*)(wr + ((size_t)(tap * 256 + m0 + mrow)) * Cin + c0 + cq);
    }
    __syncthreads();
    // ---- compute: 9 taps, 16 MFMA each ----
    #pragma unroll
    for (int ky = 0; ky < 3; ky++) {
      #pragma unroll
      for (int kx = 0; kx < 3; kx++) {
        const int off = (ky - 1) * 50 + (kx - 1);
        const unsigned short* Ab = As + (ky * 3 + kx) * 2560;
        short8_t a[4], b[4];
        #pragma unroll
        for (int ti = 0; ti < 4; ti++)
          a[ti] = *(const short8_t*)(Ab + (ti * 16 + lm) * 40 + lk);
        #pragma unroll
        for (int tj = 0; tj < 4; tj++)
          b[tj] = *(const short8_t*)(Bs + (qoff[tj] + off) * 40 + lk);
        #pragma unroll
        for (int ti = 0; ti < 4; ti++)
          #pragma unroll
          for (int tj = 0; tj < 4; tj++)
            acc[ti][tj] = __builtin_amdgcn_mfma_f32_16x16x32_bf16(
                a[ti], b[tj], acc[ti][tj], 0, 0, 0);
      }
    }
  }

  // ---- epilogue: BN + ReLU ----
  #pragma unroll
  for (int ti = 0; ti < 4; ti++) {
    const int m = m0 + ti * 16 + ((ln >> 4) << 2);
    float inv[4], add[4];
    #pragma unroll
    for (int r = 0; r < 4; r++) {
      inv[r] = gamma[m + r] * rsqrtf(var[m + r] + 1e-5f);
      add[r] = beta[m + r] - mean[m + r] * inv[r];
    }
    #pragma unroll
    for (int tj = 0; tj < 4; tj++) {
      const int p = p0 + wv * 64 + tj * 16 + lm;
      float vr[4];
      #pragma unroll
      for (int r = 0; r < 4; r++)
        vr[r] = relu_(acc[ti][tj][r] * inv[r] + add[r]);
      if (OUT_BF16) {
        // act1 [b][p][256] bf16
        uint2 o;
        o.x = pack2(vr[0], vr[1]);
        o.y = pack2(vr[2], vr[3]);
        *(uint2*)((unsigned short*)outv + ((size_t)(bb * PPX + p)) * 256 + m) = o;
      } else {
        // out [b][c][p] fp32
        #pragma unroll
        for (int r = 0; r < 4; r++)
          ((float*)outv)[((size_t)(bb * 256 + m + r)) * PPX + p] = vr[r];
      }
    }
  }
}

// ---------------------------------------------------------------------------
// pool3(avg/max of xt bf16) * sigmoid(act1) -> padded bf16 cat [pos][512]
// Threads: c fast (coalesced on [pos][chan] tensors).
// ---------------------------------------------------------------------------
__global__ __launch_bounds__(256) void pool_gate_cat(
    const unsigned short* __restrict__ xt, const unsigned short* __restrict__ act1b,
    unsigned short* __restrict__ cat_p)
{
  const int idx = blockIdx.x * 256 + threadIdx.x;   // < NTOT
  const int c = idx & 255;
  const int rest = idx >> 8;
  const int p = rest % PPX;
  const int b = rest / PPX;
  const int y = p / 48, x = p - (p / 48) * 48;
  const unsigned short* base = xt + ((size_t)b * PPX) * 256 + c;
  float s = 0.f, mxv = -1e30f;
  #pragma unroll
  for (int dy = -1; dy <= 1; dy++) {
    const int yy = y + dy;
    if (yy < 0 || yy >= 48) continue;
    #pragma unroll
    for (int dx = -1; dx <= 1; dx++) {
      const int xx = x + dx;
      if (xx < 0 || xx >= 48) continue;
      const float f = bf2f(base[(size_t)(yy * 48 + xx) * 256]);
      s += f; mxv = fmaxf(mxv, f);
    }
  }
  const float g = bf2f(act1b[(size_t)idx]);
  const float gate = 1.f / (1.f + expf(-g));
  const size_t pp = (size_t)(y + 1) * 50 + (x + 1);
  unsigned short* crow = cat_p + ((size_t)b * PADIMG + pp) * 512;
  crow[c]       = f2bf(mxv * gate);                 // max half
  crow[c + 256] = f2bf(s * (1.f / 9.f) * gate);     // avg half
}

// ---------------------------------------------------------------------------
extern "C" void kernel_launch(void* const* d_in, const int* in_sizes, int n_in,
                              void* d_out, int out_size, void* d_ws, size_t ws_size,
                              hipStream_t stream)
{
  const float* ftr  = (const float*)d_in[0];
  const float* wq   = (const float*)d_in[1];
  const float* bq   = (const float*)d_in[2];
  const float* wk   = (const float*)d_in[3];
  const float* bk   = (const float*)d_in[4];
  const float* wv   = (const float*)d_in[5];
  const float* bv   = (const float*)d_in[6];
  const float* delta= (const float*)d_in[7];
  const float* w1   = (const float*)d_in[8];
  const float* g1   = (const float*)d_in[9];
  const float* b1   = (const float*)d_in[10];
  const float* m1   = (const float*)d_in[11];
  const float* v1   = (const float*)d_in[12];
  const float* w2   = (const float*)d_in[13];
  const float* g2   = (const float*)d_in[14];
  const float* b2   = (const float*)d_in[15];
  const float* m2   = (const float*)d_in[16];
  const float* v2   = (const float*)d_in[17];
  float* out = (float*)d_out;

  // ---- workspace layout (shorts) ----
  const size_t XT = (size_t)NTOT;
  unsigned short* base = (unsigned short*)d_ws;
  unsigned short* xt   = base;
  unsigned short* qt   = xt  + XT;
  unsigned short* kt   = qt  + XT;
  unsigned short* vbuf = kt  + XT;
  unsigned short* wqb  = vbuf + XT;
  unsigned short* wkb  = wqb + 65536;
  unsigned short* wvb  = wkb + 65536;
  unsigned short* wr1  = wvb + 65536;
  unsigned short* wr2  = wr1 + (size_t)9 * 256 * 256;
  unsigned short* attn_p = wr2 + (size_t)9 * 256 * 512;      // [b][2500][256]
  unsigned short* act1b  = attn_p + (size_t)NB * PADIMG * 256; // [b][2304][256]
  unsigned short* cat_p  = act1b + XT;                        // [b][2500][512]
  unsigned short* St     = cat_p + (size_t)NB * PADIMG * 512;

  const size_t head_bytes = (size_t)((char*)St - (char*)base);
  const bool modeA = ws_size >= head_bytes + (size_t)NB * PSQ * 2;

  const size_t ATTN_P_SH = (size_t)NB * PADIMG * 256;
  const size_t CAT_P_SH  = (size_t)NB * PADIMG * 512;

  // ---- weight preps ----
  castw<<<dim3(256), 256, 0, stream>>>(wq, wqb, 65536);
  castw<<<dim3(256), 256, 0, stream>>>(wk, wkb, 65536);
  castw<<<dim3(256), 256, 0, stream>>>(wv, wvb, 65536);
  repack_w<<<dim3((9 * 256 * 256 + 255) / 256), 256, 0, stream>>>(w1, wr1, 256);
  repack_w<<<dim3((9 * 256 * 512 + 255) / 256), 256, 0, stream>>>(w2, wr2, 512);

  // ---- x transpose ----
  transpose_cast<<<dim3(36, 4, 8), 256, 0, stream>>>(ftr, xt);

  // ---- QKV ----
  gemm_nt<1><<<dim3(2, 18, 8), 256, 0, stream>>>(wqb, 0L, xt, (long)CPb, qt, (long)CPb, 256, bq);
  gemm_nt<1><<<dim3(2, 18, 8), 256, 0, stream>>>(wkb, 0L, xt, (long)CPb, kt, (long)CPb, 256, bk);
  gemm_nt<2><<<dim3(18, 2, 8), 256, 0, stream>>>(xt, (long)CPb, wvb, 0L, vbuf, (long)CPb, PPX, bv);

  hipMemsetAsync(attn_p, 0, ATTN_P_SH * 2, stream);

  if (modeA) {
    gemm_nt<0><<<dim3(18, 18, 8), 256, 0, stream>>>(qt, (long)CPb, kt, (long)CPb,
                                                    St, (long)PSQ, PPX, nullptr);
    rowstats<<<dim3(PPX, 8), 256, 0, stream>>>(St, (long)PSQ);
    pv_mfma<<<dim3(2, 36, 8), 128, 0, stream>>>(vbuf, St, (long)PSQ, ftr, delta, attn_p, 0);
  } else {
    for (int b = 0; b < NB; b++) {
      gemm_nt<0><<<dim3(18, 18, 1), 256, 0, stream>>>(
          qt + (size_t)b * CPb, 0L, kt + (size_t)b * CPb, 0L, St, 0L, PPX, nullptr);
      rowstats<<<dim3(PPX, 1), 256, 0, stream>>>(St, 0L);
      pv_mfma<<<dim3(2, 36, 1), 128, 0, stream>>>(vbuf, St, 0L, ftr, delta, attn_p, b);
    }
  }

  // ---- conv1 + BN + ReLU -> bf16 act1b [p][c] ----
  conv_mfma<true><<<dim3(144, 4), 128, 0, stream>>>(
      attn_p, 256, wr1, g1, b1, m1, v1, (void*)act1b);

  // ---- pool + gate + concat -> padded bf16 cat [pos][512] ----
  hipMemsetAsync(cat_p, 0, CAT_P_SH * 2, stream);
  pool_gate_cat<<<dim3(NTOT / 256), 256, 0, stream>>>(xt, act1b, cat_p);

  // ---- conv2 + BN + ReLU -> fp32 out ----
  conv_mfma<false><<<dim3(144, 4), 128, 0, stream>>>(
      cat_p, 512, wr2, g2, b2, m2, v2, (void*)out);
}

// Round 5
// 453.681 us; speedup vs baseline: 4.6929x; 1.2430x over previous
//
#include <hip/hip_runtime.h>
#include <math.h>

// Problem constants
#define NB   8
#define CCH  256
#define PPX  2304            // 48*48
#define CPb  (CCH*PPX)       // per-batch C*P = 589824
#define NTOT (NB*CPb)        // 4718592
#define PSQ  (PPX*PPX)       // 5308416
#define PADIMG 2500          // 50*50 padded image

typedef short short8_t __attribute__((ext_vector_type(8)));
typedef float f4_t __attribute__((ext_vector_type(4)));

__device__ __forceinline__ float relu_(float x){ return x > 0.f ? x : 0.f; }

__device__ __forceinline__ unsigned short f2bf(float f) {
  unsigned int u = __builtin_bit_cast(unsigned int, f);
  u += 0x7fffu + ((u >> 16) & 1u);
  return (unsigned short)(u >> 16);
}
__device__ __forceinline__ float bf2f(unsigned short h) {
  unsigned int u = ((unsigned int)h) << 16;
  return __builtin_bit_cast(float, u);
}
__device__ __forceinline__ unsigned int pack2(float a, float b) {
  return (unsigned int)f2bf(a) | ((unsigned int)f2bf(b) << 16);
}

// async global -> LDS, 16B per lane, wave-uniform LDS base (lane spreads x16B)
__device__ __forceinline__ void gll16(const void* g, void* l) {
  __builtin_amdgcn_global_load_lds(
      (const __attribute__((address_space(1))) unsigned int*)g,
      (__attribute__((address_space(3))) unsigned int*)l, 16, 0, 0);
}

// ---------------------------------------------------------------------------
// small casts / repacks
// ---------------------------------------------------------------------------
__global__ __launch_bounds__(256) void castw(
    const float* __restrict__ w, unsigned short* __restrict__ o, int n)
{
  const int i = blockIdx.x * 256 + threadIdx.x;
  if (i < n) o[i] = f2bf(w[i]);
}

__global__ __launch_bounds__(256) void repack_w(
    const float* __restrict__ w, unsigned short* __restrict__ wr, int Cin)
{
  const int idx = blockIdx.x * 256 + threadIdx.x;
  const int total = 9 * 256 * Cin;
  if (idx >= total) return;
  const int c = idx % Cin;
  const int rest = idx / Cin;
  const int o = rest % 256;
  const int tap = rest / 256;
  wr[idx] = f2bf(w[((size_t)o * Cin + c) * 9 + tap]);
}

// ftr [b][c][p] fp32 -> x_t [b][p][c] bf16
__global__ __launch_bounds__(256) void transpose_cast(
    const float* __restrict__ ftr, unsigned short* __restrict__ xt)
{
  const int p0 = blockIdx.x * 64, c0 = blockIdx.y * 64, b = blockIdx.z;
  const int t = threadIdx.x;
  __shared__ unsigned short T[64][72];
  #pragma unroll
  for (int pass = 0; pass < 4; pass++) {
    const int cr = pass * 16 + (t >> 4);
    const int pc = (t & 15) * 4;
    float4 v = *(const float4*)&ftr[((size_t)(b * 256 + c0 + cr)) * PPX + p0 + pc];
    T[pc + 0][cr] = f2bf(v.x); T[pc + 1][cr] = f2bf(v.y);
    T[pc + 2][cr] = f2bf(v.z); T[pc + 3][cr] = f2bf(v.w);
  }
  __syncthreads();
  #pragma unroll
  for (int pass = 0; pass < 2; pass++) {
    const int pr = pass * 32 + (t >> 3);
    const int cc = (t & 7) * 8;
    *(uint4*)&xt[((size_t)(b * PPX + p0 + pr)) * 256 + c0 + cc] = *(const uint4*)&T[pr][cc];
  }
}

// ---------------------------------------------------------------------------
// Generic bf16 MFMA GEMM: O[n][m] = sum_k A[m][k]*B[n][k]
// Tile 128x128, 4 waves (2x2 of 64x64). Async LDS staging, swizzled rows.
// EPI: 0 none, 1 bias on m, 2 bias on n, 3 pv-epilogue (delta*acc+ftr -> attn_p)
// ---------------------------------------------------------------------------
template<int EPI>
__global__ __launch_bounds__(256) void gemm_nt(
    const unsigned short* __restrict__ A, long Ab,
    const unsigned short* __restrict__ B, long Bb, int K,
    unsigned short* __restrict__ O, long Ob, int ldo,
    const float* __restrict__ bias,
    const float* __restrict__ ftr, const float* __restrict__ delta, int bstart)
{
  const int t = threadIdx.x;
  const int ln = t & 63;
  const int wid = t >> 6;
  const int wm = (wid & 1) * 64, wn = (wid >> 1) * 64;
  const int lm = ln & 15, lg = ln >> 4;
  const int m0 = blockIdx.x * 128, n0 = blockIdx.y * 128;
  const long bz = blockIdx.z;
  const unsigned short* Ap = A + bz * Ab;
  const unsigned short* Bp = B + bz * Bb;

  __shared__ __align__(16) unsigned short As[128 * 32];
  __shared__ __align__(16) unsigned short Bs[128 * 32];

  // staging lane constants: lane covers row sR(+16*i), physical chan-slot sP
  const int sR = ln >> 2, sP = ln & 3;
  // fragment-read lane constant (rows wm/wn + ti*16 are 0 mod 4)
  const int fbase = lm * 32 + (((lg + (lm >> 2)) & 3) * 8);

  f4_t acc[4][4];
  #pragma unroll
  for (int i = 0; i < 4; i++)
    #pragma unroll
    for (int j = 0; j < 4; j++) acc[i][j] = (f4_t){0.f, 0.f, 0.f, 0.f};

  for (int k0 = 0; k0 < K; k0 += 32) {
    __syncthreads();
    #pragma unroll
    for (int i = wid; i < 8; i += 4) {
      const int R = i * 16 + sR;
      const int l = (sP - (R >> 2)) & 3;              // logical chan-group
      gll16(Ap + (size_t)(m0 + R) * K + k0 + l * 8, As + i * 512);
      gll16(Bp + (size_t)(n0 + R) * K + k0 + l * 8, Bs + i * 512);
    }
    __syncthreads();
    short8_t a[4], b[4];
    #pragma unroll
    for (int ti = 0; ti < 4; ti++)
      a[ti] = *(const short8_t*)(As + (wm + ti * 16) * 32 + fbase);
    #pragma unroll
    for (int tj = 0; tj < 4; tj++)
      b[tj] = *(const short8_t*)(Bs + (wn + tj * 16) * 32 + fbase);
    #pragma unroll
    for (int ti = 0; ti < 4; ti++)
      #pragma unroll
      for (int tj = 0; tj < 4; tj++)
        acc[ti][tj] = __builtin_amdgcn_mfma_f32_16x16x32_bf16(
            a[ti], b[tj], acc[ti][tj], 0, 0, 0);
  }

  if (EPI == 3) {
    const int b = bstart + (int)bz;
    const float d0 = delta[0];
    #pragma unroll
    for (int ti = 0; ti < 4; ti++) {
      const int mb = m0 + wm + ti * 16 + (lg << 2);   // channel c
      #pragma unroll
      for (int tj = 0; tj < 4; tj++) {
        const int n = n0 + wn + tj * 16 + lm;          // pixel j
        const int y = n / 48, x = n - (n / 48) * 48;
        const size_t pp = (size_t)(y + 1) * 50 + (x + 1);
        float vr[4];
        #pragma unroll
        for (int r = 0; r < 4; r++)
          vr[r] = d0 * acc[ti][tj][r] + ftr[((size_t)(b * 256 + mb + r)) * PPX + n];
        uint2 o;
        o.x = pack2(vr[0], vr[1]);
        o.y = pack2(vr[2], vr[3]);
        *(uint2*)(O + ((size_t)b * PADIMG + pp) * 256 + mb) = o;
      }
    }
  } else {
    #pragma unroll
    for (int ti = 0; ti < 4; ti++) {
      const int mb = m0 + wm + ti * 16 + (lg << 2);
      #pragma unroll
      for (int tj = 0; tj < 4; tj++) {
        const int n = n0 + wn + tj * 16 + lm;
        float add0 = 0.f, add1 = 0.f, add2 = 0.f, add3 = 0.f;
        if (EPI == 1) { add0 = bias[mb]; add1 = bias[mb+1]; add2 = bias[mb+2]; add3 = bias[mb+3]; }
        if (EPI == 2) { add0 = add1 = add2 = add3 = bias[n]; }
        uint2 o;
        o.x = pack2(acc[ti][tj][0] + add0, acc[ti][tj][1] + add1);
        o.y = pack2(acc[ti][tj][2] + add2, acc[ti][tj][3] + add3);
        *(uint2*)(O + bz * Ob + (size_t)n * ldo + mb) = o;
      }
    }
  }
}

// ---------------------------------------------------------------------------
// Row softmax of St IN PLACE: row j: W[i] = exp(s-mx)/sum  (bf16 out)
// ---------------------------------------------------------------------------
__global__ __launch_bounds__(256) void rowstats(
    unsigned short* __restrict__ St, long sstride)
{
  const int j = blockIdx.x, bb = blockIdx.y;
  unsigned short* row = St + (long)bb * sstride + (size_t)j * PPX;
  const int t = threadIdx.x;

  float v[16];
  int nv = 0;
  float m = -1e30f;
  for (int ch = t; ch < 288; ch += 256) {
    const uint4 d = *(const uint4*)(row + ch * 8);
    const unsigned int* dp = (const unsigned int*)&d;
    #pragma unroll
    for (int q = 0; q < 4; q++) {
      v[nv]     = bf2f((unsigned short)(dp[q] & 0xffffu));
      v[nv + 1] = bf2f((unsigned short)(dp[q] >> 16));
      m = fmaxf(m, fmaxf(v[nv], v[nv + 1]));
      nv += 2;
    }
  }
  __shared__ float red[256];
  red[t] = m; __syncthreads();
  for (int s = 128; s > 0; s >>= 1) {
    if (t < s) red[t] = fmaxf(red[t], red[t + s]);
    __syncthreads();
  }
  m = red[0]; __syncthreads();
  float sum = 0.f;
  for (int u = 0; u < nv; u++) { v[u] = expf(v[u] - m); sum += v[u]; }
  red[t] = sum; __syncthreads();
  for (int s = 128; s > 0; s >>= 1) {
    if (t < s) red[t] += red[t + s];
    __syncthreads();
  }
  const float inv = 1.f / red[0];
  int u = 0;
  for (int ch = t; ch < 288; ch += 256) {
    unsigned int res[4];
    #pragma unroll
    for (int q = 0; q < 4; q++) {
      res[q] = pack2(v[u] * inv, v[u + 1] * inv);
      u += 2;
    }
    *(uint4*)(row + ch * 8) = *(const uint4*)res;
  }
}

// ---------------------------------------------------------------------------
// Conv3x3 + BN + ReLU, MFMA bf16, [pos][chan] activations, async LDS staging.
// Block: 128 thr (2 waves), tile 64 Cout x 128 px, 32-chan K slices.
// ---------------------------------------------------------------------------
template<bool OUT_BF16>
__global__ __launch_bounds__(128) void conv_mfma(
    const unsigned short* __restrict__ act_p, int Cin,
    const unsigned short* __restrict__ wr,
    const float* __restrict__ gamma, const float* __restrict__ beta,
    const float* __restrict__ mean,  const float* __restrict__ var,
    void* __restrict__ outv)
{
  const int t  = threadIdx.x;
  const int wv = t >> 6;
  const int ln = t & 63;
  const int lm = ln & 15;
  const int lg = ln >> 4;

  const int bx = blockIdx.x;      // 144 = 8 images * 18 pixel-tiles
  const int bb = bx / 18;
  const int p0 = (bx % 18) * 128;
  const int m0 = blockIdx.y * 64;

  __shared__ __align__(16) unsigned short Bs[240 * 32];    // [pos][c] 15.4 KB
  __shared__ __align__(16) unsigned short As[9 * 64 * 32]; // [tap][m][c] 36.9 KB

  const int qbase = p0 + 2 * (p0 / 48);    // q(p0) - 51
  int qoff[4];
  #pragma unroll
  for (int tj = 0; tj < 4; tj++) {
    const int p = p0 + wv * 64 + tj * 16 + lm;
    qoff[tj] = (p - p0) + 2 * (p / 48 - p0 / 48) + 51;
  }

  const int sR = ln >> 2, sP = ln & 3;
  const int abase = lm * 32 + (((lg + (lm >> 2)) & 3) * 8);  // A frag lane const

  f4_t acc[4][4];
  #pragma unroll
  for (int i = 0; i < 4; i++)
    #pragma unroll
    for (int j = 0; j < 4; j++) acc[i][j] = (f4_t){0.f, 0.f, 0.f, 0.f};

  for (int c0 = 0; c0 < Cin; c0 += 32) {
    __syncthreads();
    // ---- stage B: 240 pos x 32 chans, 15 async instructions ----
    const unsigned short* gb = act_p + ((size_t)bb * PADIMG) * Cin + c0;
    for (int i = wv; i < 15; i += 2) {
      const int R = i * 16 + sR;
      int Rg = qbase + R;
      if (Rg > PADIMG - 1) Rg = PADIMG - 1;              // clamp tail OOB
      const int l = (sP - (R >> 2)) & 3;
      gll16(gb + (size_t)Rg * Cin + l * 8, Bs + i * 512);
    }
    // ---- stage A: 9 taps x 64 m x 32 chans, 36 async instructions ----
    for (int i = wv; i < 36; i += 2) {
      const int R = i * 16 + sR;                          // 0..575
      const int tap = R >> 6, mr = R & 63;
      const int l = (sP - (R >> 2)) & 3;
      gll16(wr + ((size_t)(tap * 256 + m0 + mr)) * Cin + c0 + l * 8, As + i * 512);
    }
    __syncthreads();
    // ---- compute: 9 taps, 16 MFMA each ----
    #pragma unroll
    for (int ky = 0; ky < 3; ky++) {
      #pragma unroll
      for (int kx = 0; kx < 3; kx++) {
        const int off = (ky - 1) * 50 + (kx - 1);
        const int tap = ky * 3 + kx;
        short8_t a[4], b[4];
        #pragma unroll
        for (int ti = 0; ti < 4; ti++)
          a[ti] = *(const short8_t*)(As + tap * 2048 + ti * 512 + abase);
        #pragma unroll
        for (int tj = 0; tj < 4; tj++) {
          const int R = qoff[tj] + off;
          const int slot = (lg + (R >> 2)) & 3;
          b[tj] = *(const short8_t*)(Bs + R * 32 + slot * 8);
        }
        #pragma unroll
        for (int ti = 0; ti < 4; ti++)
          #pragma unroll
          for (int tj = 0; tj < 4; tj++)
            acc[ti][tj] = __builtin_amdgcn_mfma_f32_16x16x32_bf16(
                a[ti], b[tj], acc[ti][tj], 0, 0, 0);
      }
    }
  }

  // ---- epilogue: BN + ReLU ----
  #pragma unroll
  for (int ti = 0; ti < 4; ti++) {
    const int m = m0 + ti * 16 + (lg << 2);
    float inv[4], add[4];
    #pragma unroll
    for (int r = 0; r < 4; r++) {
      inv[r] = gamma[m + r] * rsqrtf(var[m + r] + 1e-5f);
      add[r] = beta[m + r] - mean[m + r] * inv[r];
    }
    #pragma unroll
    for (int tj = 0; tj < 4; tj++) {
      const int p = p0 + wv * 64 + tj * 16 + lm;
      float vr[4];
      #pragma unroll
      for (int r = 0; r < 4; r++)
        vr[r] = relu_(acc[ti][tj][r] * inv[r] + add[r]);
      if (OUT_BF16) {
        uint2 o;
        o.x = pack2(vr[0], vr[1]);
        o.y = pack2(vr[2], vr[3]);
        *(uint2*)((unsigned short*)outv + ((size_t)(bb * PPX + p)) * 256 + m) = o;
      } else {
        #pragma unroll
        for (int r = 0; r < 4; r++)
          ((float*)outv)[((size_t)(bb * 256 + m + r)) * PPX + p] = vr[r];
      }
    }
  }
}

// ---------------------------------------------------------------------------
// pool3(avg/max of xt bf16) * sigmoid(act1) -> padded bf16 cat [pos][512]
// ---------------------------------------------------------------------------
__global__ __launch_bounds__(256) void pool_gate_cat(
    const unsigned short* __restrict__ xt, const unsigned short* __restrict__ act1b,
    unsigned short* __restrict__ cat_p)
{
  const int idx = blockIdx.x * 256 + threadIdx.x;   // < NTOT
  const int c = idx & 255;
  const int rest = idx >> 8;
  const int p = rest % PPX;
  const int b = rest / PPX;
  const int y = p / 48, x = p - (p / 48) * 48;
  const unsigned short* base = xt + ((size_t)b * PPX) * 256 + c;
  float s = 0.f, mxv = -1e30f;
  #pragma unroll
  for (int dy = -1; dy <= 1; dy++) {
    const int yy = y + dy;
    if (yy < 0 || yy >= 48) continue;
    #pragma unroll
    for (int dx = -1; dx <= 1; dx++) {
      const int xx = x + dx;
      if (xx < 0 || xx >= 48) continue;
      const float f = bf2f(base[(size_t)(yy * 48 + xx) * 256]);
      s += f; mxv = fmaxf(mxv, f);
    }
  }
  const float g = bf2f(act1b[(size_t)idx]);
  const float gate = 1.f / (1.f + expf(-g));
  const size_t pp = (size_t)(y + 1) * 50 + (x + 1);
  unsigned short* crow = cat_p + ((size_t)b * PADIMG + pp) * 512;
  crow[c]       = f2bf(mxv * gate);
  crow[c + 256] = f2bf(s * (1.f / 9.f) * gate);
}

// ---------------------------------------------------------------------------
extern "C" void kernel_launch(void* const* d_in, const int* in_sizes, int n_in,
                              void* d_out, int out_size, void* d_ws, size_t ws_size,
                              hipStream_t stream)
{
  const float* ftr  = (const float*)d_in[0];
  const float* wq   = (const float*)d_in[1];
  const float* bq   = (const float*)d_in[2];
  const float* wk   = (const float*)d_in[3];
  const float* bk   = (const float*)d_in[4];
  const float* wv   = (const float*)d_in[5];
  const float* bv   = (const float*)d_in[6];
  const float* delta= (const float*)d_in[7];
  const float* w1   = (const float*)d_in[8];
  const float* g1   = (const float*)d_in[9];
  const float* b1   = (const float*)d_in[10];
  const float* m1   = (const float*)d_in[11];
  const float* v1   = (const float*)d_in[12];
  const float* w2   = (const float*)d_in[13];
  const float* g2   = (const float*)d_in[14];
  const float* b2   = (const float*)d_in[15];
  const float* m2   = (const float*)d_in[16];
  const float* v2   = (const float*)d_in[17];
  float* out = (float*)d_out;

  // ---- workspace layout (shorts) ----
  const size_t XT = (size_t)NTOT;
  unsigned short* base = (unsigned short*)d_ws;
  unsigned short* xt   = base;
  unsigned short* qt   = xt  + XT;
  unsigned short* kt   = qt  + XT;
  unsigned short* vbuf = kt  + XT;
  unsigned short* wqb  = vbuf + XT;
  unsigned short* wkb  = wqb + 65536;
  unsigned short* wvb  = wkb + 65536;
  unsigned short* wr1  = wvb + 65536;
  unsigned short* wr2  = wr1 + (size_t)9 * 256 * 256;
  unsigned short* attn_p = wr2 + (size_t)9 * 256 * 512;        // [b][2500][256]
  unsigned short* act1b  = attn_p + (size_t)NB * PADIMG * 256; // [b][2304][256]
  unsigned short* cat_p  = act1b + XT;                         // [b][2500][512]
  unsigned short* St     = cat_p + (size_t)NB * PADIMG * 512;

  const size_t head_bytes = (size_t)((char*)St - (char*)base);
  const bool modeA = ws_size >= head_bytes + (size_t)NB * PSQ * 2;

  const size_t ATTN_P_SH = (size_t)NB * PADIMG * 256;
  const size_t CAT_P_SH  = (size_t)NB * PADIMG * 512;

  // ---- weight preps ----
  castw<<<dim3(256), 256, 0, stream>>>(wq, wqb, 65536);
  castw<<<dim3(256), 256, 0, stream>>>(wk, wkb, 65536);
  castw<<<dim3(256), 256, 0, stream>>>(wv, wvb, 65536);
  repack_w<<<dim3((9 * 256 * 256 + 255) / 256), 256, 0, stream>>>(w1, wr1, 256);
  repack_w<<<dim3((9 * 256 * 512 + 255) / 256), 256, 0, stream>>>(w2, wr2, 512);

  // ---- x transpose ----
  transpose_cast<<<dim3(36, 4, 8), 256, 0, stream>>>(ftr, xt);

  // ---- QKV ----
  gemm_nt<1><<<dim3(2, 18, 8), 256, 0, stream>>>(
      wqb, 0L, xt, (long)CPb, 256, qt, (long)CPb, 256, bq, nullptr, nullptr, 0);
  gemm_nt<1><<<dim3(2, 18, 8), 256, 0, stream>>>(
      wkb, 0L, xt, (long)CPb, 256, kt, (long)CPb, 256, bk, nullptr, nullptr, 0);
  gemm_nt<2><<<dim3(18, 2, 8), 256, 0, stream>>>(
      xt, (long)CPb, wvb, 0L, 256, vbuf, (long)CPb, PPX, bv, nullptr, nullptr, 0);

  hipMemsetAsync(attn_p, 0, ATTN_P_SH * 2, stream);

  if (modeA) {
    gemm_nt<0><<<dim3(18, 18, 8), 256, 0, stream>>>(
        qt, (long)CPb, kt, (long)CPb, 256, St, (long)PSQ, PPX, nullptr, nullptr, nullptr, 0);
    rowstats<<<dim3(PPX, 8), 256, 0, stream>>>(St, (long)PSQ);
    gemm_nt<3><<<dim3(2, 18, 8), 256, 0, stream>>>(
        vbuf, (long)CPb, St, (long)PSQ, PPX, attn_p, 0L, 0, nullptr, ftr, delta, 0);
  } else {
    for (int b = 0; b < NB; b++) {
      gemm_nt<0><<<dim3(18, 18, 1), 256, 0, stream>>>(
          qt + (size_t)b * CPb, 0L, kt + (size_t)b * CPb, 0L, 256,
          St, 0L, PPX, nullptr, nullptr, nullptr, 0);
      rowstats<<<dim3(PPX, 1), 256, 0, stream>>>(St, 0L);
      gemm_nt<3><<<dim3(2, 18, 1), 256, 0, stream>>>(
          vbuf + (size_t)b * CPb, 0L, St, 0L, PPX, attn_p, 0L, 0, nullptr, ftr, delta, b);
    }
  }

  // ---- conv1 + BN + ReLU -> bf16 act1b [p][c] ----
  conv_mfma<true><<<dim3(144, 4), 128, 0, stream>>>(
      attn_p, 256, wr1, g1, b1, m1, v1, (void*)act1b);

  // ---- pool + gate + concat -> padded bf16 cat [pos][512] ----
  hipMemsetAsync(cat_p, 0, CAT_P_SH * 2, stream);
  pool_gate_cat<<<dim3(NTOT / 256), 256, 0, stream>>>(xt, act1b, cat_p);

  // ---- conv2 + BN + ReLU -> fp32 out ----
  conv_mfma<false><<<dim3(144, 4), 128, 0, stream>>>(
      cat_p, 512, wr2, g2, b2, m2, v2, (void*)out);
}